// Round 1
// baseline (2977.254 us; speedup 1.0000x reference)
//
#include <hip/hip_runtime.h>
#include <hip/hip_bf16.h>
#include <math.h>

// Problem constants (MixedHead): B=16,T=256 -> BT=4096; INP=1536; E=512; H=8; N=16; D=64.
#define BTOT 4096
#define INP  1536
#define EDIM 512
#define HDIM 64
#define NHEAD 8
#define NTOK 16
#define KVW  16384   // 2*E*N
#define ENW  8192    // E*N
#define FFH  1024    // 2*E

// ---------------------------------------------------------------------------
// Generic f32 tiled GEMM: C[M,Nc] = epilogue(scale*A@B + bias [+gelu] [+res])
// BM x BN tile, BK=16, 256 threads, TM x TN per-thread micro-tile.
// Column micro-tile is split in groups of 4 at stride 64 (bank-conflict-free).
// Requires: M % BM == 0, Nc % BN == 0, K % 16 == 0, BM == 16*TM, BN == 16*TN.
// ---------------------------------------------------------------------------
template <int BM, int BN, int TM, int TN, bool GELU>
__global__ __launch_bounds__(256) void gemm_k(
    const float* __restrict__ A, int lda,
    const float* __restrict__ B, int ldb,
    float* __restrict__ C, int ldc, int K,
    const float* __restrict__ bias,
    const float* __restrict__ res, int ldr,
    float scale)
{
    constexpr int BK = 16;
    static_assert(BM == 16 * TM && BN == 16 * TN, "tile mismatch");
    __shared__ float As[BK][BM];   // A transposed: As[k][m]
    __shared__ float Bs[BK][BN];

    const int tid = threadIdx.x;
    const int tx = tid & 15;
    const int ty = tid >> 4;
    const int brow = blockIdx.y * BM;
    const int bcol = blockIdx.x * BN;

    float acc[TM][TN];
#pragma unroll
    for (int i = 0; i < TM; ++i)
#pragma unroll
        for (int j = 0; j < TN; ++j) acc[i][j] = 0.f;

    constexpr int A_F4 = (BM * BK) / 1024;  // float4 loads per thread
    constexpr int B_F4 = (BN * BK) / 1024;

    for (int k0 = 0; k0 < K; k0 += BK) {
#pragma unroll
        for (int l = 0; l < A_F4; ++l) {
            int idx = tid + l * 256;
            int r = idx >> 2;      // BK/4 == 4 float4 per row
            int kq = idx & 3;
            float4 v = *reinterpret_cast<const float4*>(
                A + (size_t)(brow + r) * lda + k0 + kq * 4);
            As[kq * 4 + 0][r] = v.x;
            As[kq * 4 + 1][r] = v.y;
            As[kq * 4 + 2][r] = v.z;
            As[kq * 4 + 3][r] = v.w;
        }
#pragma unroll
        for (int l = 0; l < B_F4; ++l) {
            int idx = tid + l * 256;
            int kk = idx / (BN / 4);
            int nq = idx % (BN / 4);
            *reinterpret_cast<float4*>(&Bs[kk][nq * 4]) =
                *reinterpret_cast<const float4*>(
                    B + (size_t)(k0 + kk) * ldb + bcol + nq * 4);
        }
        __syncthreads();
#pragma unroll
        for (int kk = 0; kk < BK; ++kk) {
            float a[TM], b[TN];
#pragma unroll
            for (int i = 0; i < TM; ++i) a[i] = As[kk][ty * TM + i];
#pragma unroll
            for (int g = 0; g < TN / 4; ++g)
#pragma unroll
                for (int j = 0; j < 4; ++j)
                    b[g * 4 + j] = Bs[kk][g * 64 + tx * 4 + j];
#pragma unroll
            for (int i = 0; i < TM; ++i)
#pragma unroll
                for (int j = 0; j < TN; ++j)
                    acc[i][j] = fmaf(a[i], b[j], acc[i][j]);
        }
        __syncthreads();
    }

#pragma unroll
    for (int i = 0; i < TM; ++i) {
        size_t r = (size_t)brow + ty * TM + i;
#pragma unroll
        for (int g = 0; g < TN / 4; ++g) {
            size_t c0 = (size_t)bcol + g * 64 + tx * 4;
            float v4[4];
#pragma unroll
            for (int j = 0; j < 4; ++j) {
                float v = acc[i][g * 4 + j] * scale;
                if (bias) v += bias[c0 + j];
                if (GELU) v = 0.5f * v * (1.f + erff(v * 0.70710678118654752f));
                if (res) v += res[r * (size_t)ldr + c0 + j];
                v4[j] = v;
            }
            *reinterpret_cast<float4*>(C + r * (size_t)ldc + c0) =
                make_float4(v4[0], v4[1], v4[2], v4[3]);
        }
    }
}

// ---------------------------------------------------------------------------
// Layer-0 attend: per (bt, h): dots[m] = SCALE * q . k_m (16 of them),
// a = log_softmax(dots), o[d] = sum_m a[m] * v[m,d].
// kv chunk layout: kv[bt][n*512 + h*64 + d] (k) and +8192 (v).
// One block = one bt (512 threads, wave h handles head h, lane = d).
// ---------------------------------------------------------------------------
__global__ __launch_bounds__(512) void attend0_k(
    const float* __restrict__ kv, const float* __restrict__ emb,
    const int* __restrict__ targets, float* __restrict__ o)
{
    const int bt = blockIdx.x;
    const int lane = threadIdx.x & 63;
    const int h = threadIdx.x >> 6;
    const int t = targets[bt];
    const float q = emb[t * EDIM + h * HDIM + lane];
    const float* kb = kv + (size_t)bt * KVW + h * HDIM + lane;

    float dots[NTOK];
#pragma unroll
    for (int m = 0; m < NTOK; ++m) {
        float p = q * kb[m * EDIM];
#pragma unroll
        for (int off = 32; off; off >>= 1) p += __shfl_xor(p, off, 64);
        dots[m] = p * 0.125f;  // SCALE = 64^-0.5
    }
    float mx = dots[0];
#pragma unroll
    for (int m = 1; m < NTOK; ++m) mx = fmaxf(mx, dots[m]);
    float s = 0.f;
#pragma unroll
    for (int m = 0; m < NTOK; ++m) s += expf(dots[m] - mx);
    const float lse = mx + logf(s);

    float acc = 0.f;
    const float* vb = kb + ENW;
#pragma unroll
    for (int m = 0; m < NTOK; ++m) acc = fmaf(dots[m] - lse, vb[m * EDIM], acc);
    o[(size_t)bt * EDIM + h * HDIM + lane] = acc;
}

// ---------------------------------------------------------------------------
// Row LayerNorm over E=512: one wave per row, 8 elems per lane.
// ---------------------------------------------------------------------------
__global__ __launch_bounds__(256) void ln_k(
    const float* __restrict__ x, const float* __restrict__ g,
    const float* __restrict__ b, float* __restrict__ y)
{
    const int row = blockIdx.x * 4 + (threadIdx.x >> 6);
    const int lane = threadIdx.x & 63;
    const float* xr = x + (size_t)row * EDIM + lane * 8;
    float4 a0 = *reinterpret_cast<const float4*>(xr);
    float4 a1 = *reinterpret_cast<const float4*>(xr + 4);
    float v[8] = {a0.x, a0.y, a0.z, a0.w, a1.x, a1.y, a1.z, a1.w};

    float s = 0.f;
#pragma unroll
    for (int j = 0; j < 8; ++j) s += v[j];
#pragma unroll
    for (int off = 32; off; off >>= 1) s += __shfl_xor(s, off, 64);
    const float m = s * (1.f / 512.f);

    float q = 0.f;
#pragma unroll
    for (int j = 0; j < 8; ++j) { float d = v[j] - m; q = fmaf(d, d, q); }
#pragma unroll
    for (int off = 32; off; off >>= 1) q += __shfl_xor(q, off, 64);
    const float inv = rsqrtf(q * (1.f / 512.f) + 1e-5f);

    const int c = lane * 8;
    float4 g0 = *reinterpret_cast<const float4*>(g + c);
    float4 g1 = *reinterpret_cast<const float4*>(g + c + 4);
    float4 b0 = *reinterpret_cast<const float4*>(b + c);
    float4 b1 = *reinterpret_cast<const float4*>(b + c + 4);
    float gg[8] = {g0.x, g0.y, g0.z, g0.w, g1.x, g1.y, g1.z, g1.w};
    float bb[8] = {b0.x, b0.y, b0.z, b0.w, b1.x, b1.y, b1.z, b1.w};
    float out[8];
#pragma unroll
    for (int j = 0; j < 8; ++j) out[j] = (v[j] - m) * inv * gg[j] + bb[j];
    float* yr = y + (size_t)row * EDIM + c;
    *reinterpret_cast<float4*>(yr) = make_float4(out[0], out[1], out[2], out[3]);
    *reinterpret_cast<float4*>(yr + 4) = make_float4(out[4], out[5], out[6], out[7]);
}

// ---------------------------------------------------------------------------
// Final: out[row] = x[row,:] . Wm + bm   (one wave per row)
// ---------------------------------------------------------------------------
__global__ __launch_bounds__(256) void final_k(
    const float* __restrict__ x, const float* __restrict__ Wm,
    const float* __restrict__ bm, float* __restrict__ out)
{
    const int row = blockIdx.x * 4 + (threadIdx.x >> 6);
    const int lane = threadIdx.x & 63;
    const float* xr = x + (size_t)row * EDIM + lane * 8;
    const float* wr = Wm + lane * 8;
    float s = 0.f;
#pragma unroll
    for (int j = 0; j < 8; ++j) s = fmaf(xr[j], wr[j], s);
#pragma unroll
    for (int off = 32; off; off >>= 1) s += __shfl_xor(s, off, 64);
    if (lane == 0) out[row] = s + bm[0];
}

// ---------------------------------------------------------------------------
extern "C" void kernel_launch(void* const* d_in, const int* in_sizes, int n_in,
                              void* d_out, int out_size, void* d_ws, size_t ws_size,
                              hipStream_t stream)
{
    (void)in_sizes; (void)n_in; (void)out_size;
    const float* features = (const float*)d_in[0];
    const int*   targets  = (const int*)d_in[1];
    const float* emb      = (const float*)d_in[2];
    const float* Wf       = (const float*)d_in[3];
    const float* bfv      = (const float*)d_in[4];
    const float* a0Wo     = (const float*)d_in[5];
    const float* a0bo     = (const float*)d_in[6];
    const float* Wm       = (const float*)d_in[7];
    const float* bm       = (const float*)d_in[8];
    const float *ffg[3], *ffb[3], *W1[3], *b1[3], *W2[3], *b2[3];
    for (int i = 0; i < 3; ++i) {
        ffg[i] = (const float*)d_in[9 + 6 * i];
        ffb[i] = (const float*)d_in[10 + 6 * i];
        W1[i]  = (const float*)d_in[11 + 6 * i];
        b1[i]  = (const float*)d_in[12 + 6 * i];
        W2[i]  = (const float*)d_in[13 + 6 * i];
        b2[i]  = (const float*)d_in[14 + 6 * i];
    }
    const float *ag[2], *abp[2], *aWqkv[2], *aWo[2], *abo[2];
    for (int i = 0; i < 2; ++i) {
        ag[i]    = (const float*)d_in[27 + 5 * i];
        abp[i]   = (const float*)d_in[28 + 5 * i];
        aWqkv[i] = (const float*)d_in[29 + 5 * i];
        aWo[i]   = (const float*)d_in[30 + 5 * i];
        abo[i]   = (const float*)d_in[31 + 5 * i];
    }

    // Workspace: [kv chunk | o | x | xln | h]. kv chunk size adapts to ws_size.
    const size_t vec_bytes = (size_t)BTOT * EDIM * 4;   // 8.39 MB
    const size_t h_bytes   = (size_t)BTOT * FFH * 4;    // 16.78 MB
    const size_t fixed     = 3 * vec_bytes + h_bytes;
    int CB = BTOT;
    while (CB > 128 && (size_t)CB * KVW * 4 + fixed > ws_size) CB >>= 1;

    char* w = (char*)d_ws;
    float* kvb = (float*)w; w += (size_t)CB * KVW * 4;
    float* o   = (float*)w; w += vec_bytes;
    float* x   = (float*)w; w += vec_bytes;
    float* xln = (float*)w; w += vec_bytes;
    float* hb  = (float*)w; w += h_bytes;

    const dim3 blk(256, 1, 1);

    // ---- layer 0: kv = f@Wf+bf (chunked over BT), then attend0, then @Wo+bo.
    for (int c0 = 0; c0 < BTOT; c0 += CB) {
        gemm_k<128, 128, 8, 8, false><<<dim3(KVW / 128, CB / 128), blk, 0, stream>>>(
            features + (size_t)c0 * INP, INP, Wf, KVW, kvb, KVW, INP,
            bfv, nullptr, 0, 1.f);
        attend0_k<<<CB, 512, 0, stream>>>(kvb, emb, targets + c0,
                                          o + (size_t)c0 * EDIM);
    }
    gemm_k<64, 64, 4, 4, false><<<dim3(EDIM / 64, BTOT / 64), blk, 0, stream>>>(
        o, EDIM, a0Wo, EDIM, x, EDIM, EDIM, a0bo, nullptr, 0, 1.f);

    // log_softmax of 16 equal logits = -ln(16); o = sum_m a*v = -16*ln(16)*v.
    const float CATT = -44.36141955583650f;

    auto ln = [&](const float* g, const float* b) {
        ln_k<<<BTOT / 4, 256, 0, stream>>>(x, g, b, xln);
    };
    auto ff = [&](int i) {
        ln(ffg[i], ffb[i]);
        gemm_k<64, 64, 4, 4, true><<<dim3(FFH / 64, BTOT / 64), blk, 0, stream>>>(
            xln, EDIM, W1[i], FFH, hb, FFH, EDIM, b1[i], nullptr, 0, 1.f);
        gemm_k<64, 64, 4, 4, false><<<dim3(EDIM / 64, BTOT / 64), blk, 0, stream>>>(
            hb, FFH, W2[i], EDIM, x, EDIM, FFH, b2[i], xln, EDIM, 1.f);
    };
    auto attn = [&](int i) {
        ln(ag[i], abp[i]);
        // v_ = xln @ Wqkv[:, 2E:3E]   (strided B view, no bias)
        gemm_k<64, 64, 4, 4, false><<<dim3(EDIM / 64, BTOT / 64), blk, 0, stream>>>(
            xln, EDIM, aWqkv[i] + 2 * EDIM, 3 * EDIM, o, EDIM, EDIM,
            nullptr, nullptr, 0, 1.f);
        // x = CATT*(v_ @ Wo) + bo + xln
        gemm_k<64, 64, 4, 4, false><<<dim3(EDIM / 64, BTOT / 64), blk, 0, stream>>>(
            o, EDIM, aWo[i], EDIM, x, EDIM, EDIM, abo[i], xln, EDIM, CATT);
    };

    ff(0);
    attn(0);   // att1
    ff(1);
    attn(1);   // att2
    ff(2);

    final_k<<<BTOT / 4, 256, 0, stream>>>(x, Wm, bm, (float*)d_out);
}

// Round 2
// 664.472 us; speedup vs baseline: 4.4806x; 4.4806x over previous
//
#include <hip/hip_runtime.h>
#include <math.h>

// MixedHead: B=16,T=256 -> BT=4096; INP=1536; E=512; H=8; N=16; D=64.
#define BTOT 4096
#define INP  1536
#define EDIM 512
#define NTOK 16
#define KVW  16384   // 2*E*N
#define ENW  8192    // E*N
#define FFH  1024    // 2*E

typedef __attribute__((ext_vector_type(8))) __bf16 bf16x8;
typedef __attribute__((ext_vector_type(4))) float f32x4;

__device__ __forceinline__ ushort f2bf(float f) {
    union { float f; unsigned u; } v; v.f = f;
    unsigned r = v.u + 0x7fffu + ((v.u >> 16) & 1u);
    return (ushort)(r >> 16);
}
__device__ __forceinline__ float bf2f(ushort h) {
    union { unsigned u; float f; } v; v.u = ((unsigned)h) << 16;
    return v.f;
}

// ---------------------------------------------------------------------------
// Transpose f32 [R][ld] (cols c0..c0+C) -> bf16 [C][R].  Grid (C/64, R/64).
// ---------------------------------------------------------------------------
__global__ __launch_bounds__(256) void transpose_bf16_k(
    const float* __restrict__ in, int ld, int c0, int R,
    ushort* __restrict__ out)
{
    __shared__ float t[64][65];
    const int tid = threadIdx.x;
    const int bc = blockIdx.x * 64 + c0;
    const int br = blockIdx.y * 64;
#pragma unroll
    for (int it = 0; it < 16; ++it) {
        int idx = tid + it * 256;
        int r = idx >> 6, c = idx & 63;
        t[r][c] = in[(size_t)(br + r) * ld + bc + c];
    }
    __syncthreads();
    const int C0 = blockIdx.x * 64;
#pragma unroll
    for (int it = 0; it < 8; ++it) {
        int idx = tid + it * 256;
        int cc = idx >> 5, rp = idx & 31;
        unsigned lo = f2bf(t[2 * rp][cc]);
        unsigned hi = f2bf(t[2 * rp + 1][cc]);
        *reinterpret_cast<unsigned*>(out + (size_t)(C0 + cc) * R + br + 2 * rp) =
            lo | (hi << 16);
    }
}

// f32 -> bf16 flat convert, 8 elems/thread.
__global__ __launch_bounds__(256) void conv_bf16_k(
    const float* __restrict__ in, ushort* __restrict__ out, int n8)
{
    int i = blockIdx.x * 256 + threadIdx.x;
    if (i >= n8) return;
    const float4* p = reinterpret_cast<const float4*>(in) + 2 * (size_t)i;
    float4 a = p[0], b = p[1];
    uint4 o;
    o.x = f2bf(a.x) | ((unsigned)f2bf(a.y) << 16);
    o.y = f2bf(a.z) | ((unsigned)f2bf(a.w) << 16);
    o.z = f2bf(b.x) | ((unsigned)f2bf(b.y) << 16);
    o.w = f2bf(b.z) | ((unsigned)f2bf(b.w) << 16);
    reinterpret_cast<uint4*>(out)[i] = o;
}

// ---------------------------------------------------------------------------
// bf16 MFMA GEMM (m97 structure): C[M,N] = epi(scale*A@BT^T + bias [+gelu] [+res])
// A bf16 [M][K] lda=K, BT bf16 [N][K] ldb=K. 128x128 tile, BK=64, 4 waves.
// LDS [128 rows][8 slots of 16B], XOR-swizzle slot^(row&7); staging via
// global_load_lds with pre-swizzled global source (linear LDS dest).
// ---------------------------------------------------------------------------
template <bool GELU, bool OUTBF>
__global__ __launch_bounds__(256) void gemm_mfma_k(
    const ushort* __restrict__ A, int lda,
    const ushort* __restrict__ BT, int ldb,
    void* __restrict__ Cp, int ldc, int K,
    const float* __restrict__ bias,
    const float* __restrict__ res, int ldr,
    float scale)
{
    __shared__ bf16x8 As[128][8];
    __shared__ bf16x8 Bs[128][8];
    const int tid = threadIdx.x;
    const int l   = tid & 63;
    const int w   = tid >> 6;
    const int wm  = w >> 1, wn = w & 1;
    const int brow = blockIdx.y * 128, bcol = blockIdx.x * 128;

    const int lr = l >> 3;            // row within 8-row staging segment
    const int ls = (l & 7) ^ lr;      // pre-swizzled source slot
    const ushort* Ab = A  + (size_t)(brow + w * 32 + lr) * lda + ls * 8;
    const ushort* Bb = BT + (size_t)(bcol + w * 32 + lr) * ldb + ls * 8;

    f32x4 acc[4][4];
#pragma unroll
    for (int i = 0; i < 4; ++i)
#pragma unroll
        for (int j = 0; j < 4; ++j) acc[i][j] = (f32x4)0.f;

    for (int k0 = 0; k0 < K; k0 += 64) {
#pragma unroll
        for (int i = 0; i < 4; ++i) {
            __builtin_amdgcn_global_load_lds(
                (const __attribute__((address_space(1))) void*)(Ab + (size_t)(i * 8) * lda + k0),
                (__attribute__((address_space(3))) void*)&As[w * 32 + i * 8][0],
                16, 0, 0);
            __builtin_amdgcn_global_load_lds(
                (const __attribute__((address_space(1))) void*)(Bb + (size_t)(i * 8) * ldb + k0),
                (__attribute__((address_space(3))) void*)&Bs[w * 32 + i * 8][0],
                16, 0, 0);
        }
        __syncthreads();
#pragma unroll
        for (int kh = 0; kh < 2; ++kh) {
            const int slot = (kh * 4 + (l >> 4)) ^ (l & 7);
            bf16x8 af[4], bfr[4];
#pragma unroll
            for (int mt = 0; mt < 4; ++mt)
                af[mt] = As[wm * 64 + mt * 16 + (l & 15)][slot];
#pragma unroll
            for (int nt = 0; nt < 4; ++nt)
                bfr[nt] = Bs[wn * 64 + nt * 16 + (l & 15)][slot];
#pragma unroll
            for (int mt = 0; mt < 4; ++mt)
#pragma unroll
                for (int nt = 0; nt < 4; ++nt)
                    acc[mt][nt] = __builtin_amdgcn_mfma_f32_16x16x32_bf16(
                        af[mt], bfr[nt], acc[mt][nt], 0, 0, 0);
        }
        __syncthreads();
    }

    const int cr = (l >> 4) * 4, cc = l & 15;
#pragma unroll
    for (int mt = 0; mt < 4; ++mt) {
#pragma unroll
        for (int nt = 0; nt < 4; ++nt) {
            const int gc = bcol + wn * 64 + nt * 16 + cc;
            const float bv = bias ? bias[gc] : 0.f;
#pragma unroll
            for (int r = 0; r < 4; ++r) {
                const size_t gr = (size_t)brow + wm * 64 + mt * 16 + cr + r;
                float v = acc[mt][nt][r] * scale + bv;
                if (GELU) v = 0.5f * v * (1.f + erff(v * 0.70710678118654752f));
                if (res) v += res[gr * ldr + gc];
                if (OUTBF) ((ushort*)Cp)[gr * ldc + gc] = f2bf(v);
                else       ((float*)Cp)[gr * ldc + gc]  = v;
            }
        }
    }
}

// ---------------------------------------------------------------------------
// Layer-0 attend (bf16 kv in, bf16 o out). One block per bt; wave h = head h.
// ---------------------------------------------------------------------------
__global__ __launch_bounds__(512) void attend0_k(
    const ushort* __restrict__ kv, const float* __restrict__ emb,
    const int* __restrict__ targets, ushort* __restrict__ o)
{
    const int bt = blockIdx.x;
    const int lane = threadIdx.x & 63;
    const int h = threadIdx.x >> 6;
    const int t = targets[bt];
    const float q = emb[t * EDIM + h * 64 + lane];
    const ushort* kb = kv + (size_t)bt * KVW + h * 64 + lane;

    float dots[NTOK];
#pragma unroll
    for (int m = 0; m < NTOK; ++m) {
        float p = q * bf2f(kb[m * EDIM]);
#pragma unroll
        for (int off = 32; off; off >>= 1) p += __shfl_xor(p, off, 64);
        dots[m] = p * 0.125f;  // SCALE = 64^-0.5
    }
    float mx = dots[0];
#pragma unroll
    for (int m = 1; m < NTOK; ++m) mx = fmaxf(mx, dots[m]);
    float s = 0.f;
#pragma unroll
    for (int m = 0; m < NTOK; ++m) s += expf(dots[m] - mx);
    const float lse = mx + logf(s);

    float acc = 0.f;
    const ushort* vb = kb + ENW;
#pragma unroll
    for (int m = 0; m < NTOK; ++m)
        acc = fmaf(dots[m] - lse, bf2f(vb[m * EDIM]), acc);
    o[(size_t)bt * EDIM + h * 64 + lane] = f2bf(acc);
}

// ---------------------------------------------------------------------------
// Row LayerNorm over E=512: one wave per row; emits f32 AND bf16.
// ---------------------------------------------------------------------------
__global__ __launch_bounds__(256) void ln_k(
    const float* __restrict__ x, const float* __restrict__ g,
    const float* __restrict__ b, float* __restrict__ y,
    ushort* __restrict__ yb)
{
    const int row = blockIdx.x * 4 + (threadIdx.x >> 6);
    const int lane = threadIdx.x & 63;
    const float* xr = x + (size_t)row * EDIM + lane * 8;
    float4 a0 = *reinterpret_cast<const float4*>(xr);
    float4 a1 = *reinterpret_cast<const float4*>(xr + 4);
    float v[8] = {a0.x, a0.y, a0.z, a0.w, a1.x, a1.y, a1.z, a1.w};

    float s = 0.f;
#pragma unroll
    for (int j = 0; j < 8; ++j) s += v[j];
#pragma unroll
    for (int off = 32; off; off >>= 1) s += __shfl_xor(s, off, 64);
    const float m = s * (1.f / 512.f);

    float q = 0.f;
#pragma unroll
    for (int j = 0; j < 8; ++j) { float d = v[j] - m; q = fmaf(d, d, q); }
#pragma unroll
    for (int off = 32; off; off >>= 1) q += __shfl_xor(q, off, 64);
    const float inv = rsqrtf(q * (1.f / 512.f) + 1e-5f);

    const int c = lane * 8;
    float4 g0 = *reinterpret_cast<const float4*>(g + c);
    float4 g1 = *reinterpret_cast<const float4*>(g + c + 4);
    float4 b0 = *reinterpret_cast<const float4*>(b + c);
    float4 b1 = *reinterpret_cast<const float4*>(b + c + 4);
    float gg[8] = {g0.x, g0.y, g0.z, g0.w, g1.x, g1.y, g1.z, g1.w};
    float bb[8] = {b0.x, b0.y, b0.z, b0.w, b1.x, b1.y, b1.z, b1.w};
    float out[8];
#pragma unroll
    for (int j = 0; j < 8; ++j) out[j] = (v[j] - m) * inv * gg[j] + bb[j];
    float* yr = y + (size_t)row * EDIM + c;
    *reinterpret_cast<float4*>(yr) = make_float4(out[0], out[1], out[2], out[3]);
    *reinterpret_cast<float4*>(yr + 4) = make_float4(out[4], out[5], out[6], out[7]);
    uint4 p;
    p.x = f2bf(out[0]) | ((unsigned)f2bf(out[1]) << 16);
    p.y = f2bf(out[2]) | ((unsigned)f2bf(out[3]) << 16);
    p.z = f2bf(out[4]) | ((unsigned)f2bf(out[5]) << 16);
    p.w = f2bf(out[6]) | ((unsigned)f2bf(out[7]) << 16);
    *reinterpret_cast<uint4*>(yb + (size_t)row * EDIM + c) = p;
}

// out[row] = x[row,:] . Wm + bm
__global__ __launch_bounds__(256) void final_k(
    const float* __restrict__ x, const float* __restrict__ Wm,
    const float* __restrict__ bm, float* __restrict__ out)
{
    const int row = blockIdx.x * 4 + (threadIdx.x >> 6);
    const int lane = threadIdx.x & 63;
    const float* xr = x + (size_t)row * EDIM + lane * 8;
    const float* wr = Wm + lane * 8;
    float s = 0.f;
#pragma unroll
    for (int j = 0; j < 8; ++j) s = fmaf(xr[j], wr[j], s);
#pragma unroll
    for (int off = 32; off; off >>= 1) s += __shfl_xor(s, off, 64);
    if (lane == 0) out[row] = s + bm[0];
}

// ---------------------------------------------------------------------------
extern "C" void kernel_launch(void* const* d_in, const int* in_sizes, int n_in,
                              void* d_out, int out_size, void* d_ws, size_t ws_size,
                              hipStream_t stream)
{
    (void)in_sizes; (void)n_in; (void)out_size;
    const float* features = (const float*)d_in[0];
    const int*   targets  = (const int*)d_in[1];
    const float* emb      = (const float*)d_in[2];
    const float* Wf       = (const float*)d_in[3];
    const float* bfv      = (const float*)d_in[4];
    const float* a0Wo     = (const float*)d_in[5];
    const float* a0bo     = (const float*)d_in[6];
    const float* Wm       = (const float*)d_in[7];
    const float* bm       = (const float*)d_in[8];
    const float *ffg[3], *ffb[3], *W1[3], *b1[3], *W2[3], *b2[3];
    for (int i = 0; i < 3; ++i) {
        ffg[i] = (const float*)d_in[9 + 6 * i];
        ffb[i] = (const float*)d_in[10 + 6 * i];
        W1[i]  = (const float*)d_in[11 + 6 * i];
        b1[i]  = (const float*)d_in[12 + 6 * i];
        W2[i]  = (const float*)d_in[13 + 6 * i];
        b2[i]  = (const float*)d_in[14 + 6 * i];
    }
    const float *ag[2], *abp[2], *aWqkv[2], *aWo[2], *abo[2];
    for (int i = 0; i < 2; ++i) {
        ag[i]    = (const float*)d_in[27 + 5 * i];
        abp[i]   = (const float*)d_in[28 + 5 * i];
        aWqkv[i] = (const float*)d_in[29 + 5 * i];
        aWo[i]   = (const float*)d_in[30 + 5 * i];
        abo[i]   = (const float*)d_in[31 + 5 * i];
    }

    // ---- workspace carve-up (all sizes 256B-aligned multiples) ----
    char* wsc = (char*)d_ws;
    auto alloc = [&](size_t bytes) { char* p = wsc; wsc += bytes; return p; };
    ushort* WfT   = (ushort*)alloc((size_t)KVW * INP * 2);       // 50.3 MB
    ushort* a0WoT = (ushort*)alloc((size_t)EDIM * EDIM * 2);
    ushort *W1T[3], *W2T[3], *WqkvT[2], *WoT[2];
    for (int i = 0; i < 3; ++i) {
        W1T[i] = (ushort*)alloc((size_t)FFH * EDIM * 2);
        W2T[i] = (ushort*)alloc((size_t)EDIM * FFH * 2);
    }
    for (int i = 0; i < 2; ++i) {
        WqkvT[i] = (ushort*)alloc((size_t)EDIM * EDIM * 2);
        WoT[i]   = (ushort*)alloc((size_t)EDIM * EDIM * 2);
    }
    ushort* featb = (ushort*)alloc((size_t)BTOT * INP * 2);      // 12.6 MB
    ushort* o_b   = (ushort*)alloc((size_t)BTOT * EDIM * 2);     // 4.2 MB
    float*  x     = (float*) alloc((size_t)BTOT * EDIM * 4);     // 8.4 MB
    float*  xln   = (float*) alloc((size_t)BTOT * EDIM * 4);
    ushort* xlnb  = (ushort*)alloc((size_t)BTOT * EDIM * 2);
    ushort* hb    = (ushort*)alloc((size_t)BTOT * FFH * 2);      // 8.4 MB
    const size_t fixed = (size_t)(wsc - (char*)d_ws);
    int CB = BTOT;
    while (CB > 256 && fixed + (size_t)CB * KVW * 2 > ws_size) CB >>= 1;
    ushort* kvb = (ushort*)alloc((size_t)CB * KVW * 2);

    const dim3 blk(256, 1, 1);

    // ---- prep: bf16 conversions / weight transposes ----
    conv_bf16_k<<<(BTOT * INP / 8 + 255) / 256, blk, 0, stream>>>(
        features, featb, BTOT * INP / 8);
    transpose_bf16_k<<<dim3(KVW / 64, INP / 64), blk, 0, stream>>>(
        Wf, KVW, 0, INP, WfT);
    transpose_bf16_k<<<dim3(8, 8), blk, 0, stream>>>(a0Wo, EDIM, 0, EDIM, a0WoT);
    for (int i = 0; i < 3; ++i) {
        transpose_bf16_k<<<dim3(16, 8), blk, 0, stream>>>(W1[i], FFH, 0, EDIM, W1T[i]);
        transpose_bf16_k<<<dim3(8, 16), blk, 0, stream>>>(W2[i], EDIM, 0, FFH, W2T[i]);
    }
    for (int i = 0; i < 2; ++i) {
        transpose_bf16_k<<<dim3(8, 8), blk, 0, stream>>>(aWqkv[i], 3 * EDIM, 2 * EDIM,
                                                         EDIM, WqkvT[i]);
        transpose_bf16_k<<<dim3(8, 8), blk, 0, stream>>>(aWo[i], EDIM, 0, EDIM, WoT[i]);
    }

    // ---- layer 0: kv = f@Wf+bf (bf16 out, chunked), attend0, @Wo+bo ----
    for (int c0 = 0; c0 < BTOT; c0 += CB) {
        gemm_mfma_k<false, true><<<dim3(KVW / 128, CB / 128), blk, 0, stream>>>(
            featb + (size_t)c0 * INP, INP, WfT, INP, kvb, KVW, INP,
            bfv, nullptr, 0, 1.f);
        attend0_k<<<CB, 512, 0, stream>>>(kvb, emb, targets + c0,
                                          o_b + (size_t)c0 * EDIM);
    }
    gemm_mfma_k<false, false><<<dim3(EDIM / 128, BTOT / 128), blk, 0, stream>>>(
        o_b, EDIM, a0WoT, EDIM, x, EDIM, EDIM, a0bo, nullptr, 0, 1.f);

    // log_softmax of 16 equal logits = -ln16; o = -16*ln16 * v.
    const float CATT = -44.36141955583650f;

    auto ln = [&](const float* g, const float* b) {
        ln_k<<<BTOT / 4, blk, 0, stream>>>(x, g, b, xln, xlnb);
    };
    auto ff = [&](int i) {
        ln(ffg[i], ffb[i]);
        gemm_mfma_k<true, true><<<dim3(FFH / 128, BTOT / 128), blk, 0, stream>>>(
            xlnb, EDIM, W1T[i], EDIM, hb, FFH, EDIM, b1[i], nullptr, 0, 1.f);
        gemm_mfma_k<false, false><<<dim3(EDIM / 128, BTOT / 128), blk, 0, stream>>>(
            hb, FFH, W2T[i], FFH, x, EDIM, FFH, b2[i], xln, EDIM, 1.f);
    };
    auto attn = [&](int i) {
        ln(ag[i], abp[i]);
        gemm_mfma_k<false, true><<<dim3(EDIM / 128, BTOT / 128), blk, 0, stream>>>(
            xlnb, EDIM, WqkvT[i], EDIM, o_b, EDIM, EDIM, nullptr, nullptr, 0, 1.f);
        gemm_mfma_k<false, false><<<dim3(EDIM / 128, BTOT / 128), blk, 0, stream>>>(
            o_b, EDIM, WoT[i], EDIM, x, EDIM, EDIM, abo[i], xln, EDIM, CATT);
    };

    ff(0);
    attn(0);
    ff(1);
    attn(1);
    ff(2);

    final_k<<<BTOT / 4, blk, 0, stream>>>(x, Wm, bm, (float*)d_out);
}

// Round 3
// 593.265 us; speedup vs baseline: 5.0184x; 1.1200x over previous
//
#include <hip/hip_runtime.h>
#include <math.h>

// MixedHead: B=16,T=256 -> BT=4096; INP=1536; E=512; H=8; N=16; D=64.
#define BTOT 4096
#define INP  1536
#define EDIM 512
#define NTOK 16
#define KVW  16384   // 2*E*N
#define ENW  8192    // E*N
#define FFH  1024    // 2*E

typedef __attribute__((ext_vector_type(8))) __bf16 bf16x8;
typedef __attribute__((ext_vector_type(4))) float f32x4;

__device__ __forceinline__ ushort f2bf(float f) {
    union { float f; unsigned u; } v; v.f = f;
    unsigned r = v.u + 0x7fffu + ((v.u >> 16) & 1u);
    return (ushort)(r >> 16);
}
__device__ __forceinline__ float bf2f(ushort h) {
    union { unsigned u; float f; } v; v.u = ((unsigned)h) << 16;
    return v.f;
}

// ---------------------------------------------------------------------------
// Transpose f32 [R][ld] (cols c0..c0+64*gx) -> bf16 [C][R].  Grid (C/64, R/64).
// ---------------------------------------------------------------------------
__global__ __launch_bounds__(256) void transpose_bf16_k(
    const float* __restrict__ in, int ld, int c0, int R,
    ushort* __restrict__ out)
{
    __shared__ float t[64][65];
    const int tid = threadIdx.x;
    const int bc = blockIdx.x * 64 + c0;
    const int br = blockIdx.y * 64;
#pragma unroll
    for (int it = 0; it < 16; ++it) {
        int idx = tid + it * 256;
        int r = idx >> 6, c = idx & 63;
        t[r][c] = in[(size_t)(br + r) * ld + bc + c];
    }
    __syncthreads();
    const int C0 = blockIdx.x * 64;
#pragma unroll
    for (int it = 0; it < 4; ++it) {
        int idx = tid + it * 256;          // 1024 = 64 cols x 16 row-quads
        int cc = idx >> 4, rp = idx & 15;
        uint2 w2;
        w2.x = f2bf(t[4 * rp + 0][cc]) | ((unsigned)f2bf(t[4 * rp + 1][cc]) << 16);
        w2.y = f2bf(t[4 * rp + 2][cc]) | ((unsigned)f2bf(t[4 * rp + 3][cc]) << 16);
        *reinterpret_cast<uint2*>(out + (size_t)(C0 + cc) * R + br + 4 * rp) = w2;
    }
}

// f32 -> bf16 flat convert, 8 elems/thread.
__global__ __launch_bounds__(256) void conv_bf16_k(
    const float* __restrict__ in, ushort* __restrict__ out, int n8)
{
    int i = blockIdx.x * 256 + threadIdx.x;
    if (i >= n8) return;
    const float4* p = reinterpret_cast<const float4*>(in) + 2 * (size_t)i;
    float4 a = p[0], b = p[1];
    uint4 o;
    o.x = f2bf(a.x) | ((unsigned)f2bf(a.y) << 16);
    o.y = f2bf(a.z) | ((unsigned)f2bf(a.w) << 16);
    o.z = f2bf(b.x) | ((unsigned)f2bf(b.y) << 16);
    o.w = f2bf(b.z) | ((unsigned)f2bf(b.w) << 16);
    reinterpret_cast<uint4*>(out)[i] = o;
}

// ---------------------------------------------------------------------------
// bf16 MFMA GEMM: C[M,N] = epi(scale*A@BT^T + bias [+gelu] [+res])
// A bf16 [M][K] lda=K, BT bf16 [N][K] ldb=K. BMxBN tile, BK=64, NW waves,
// per-wave WMxWN output. LDS [rows][8 x 16B], XOR slot^(row&7); staging via
// global_load_lds with pre-swizzled global source. Bijective XCD swizzle.
// ---------------------------------------------------------------------------
template <int BM, int BN, int WM, int WN, int NW, bool GELU, bool OUTBF>
__global__ __launch_bounds__(NW * 64) void gemm_mfma_k(
    const ushort* __restrict__ A, int lda,
    const ushort* __restrict__ BT, int ldb,
    void* __restrict__ Cp, int ldc, int K,
    const float* __restrict__ bias,
    const float* __restrict__ res, int ldr,
    float scale)
{
    static_assert((BM / WM) * (BN / WN) == NW, "wave grid");
    static_assert(BM % (NW * 8) == 0 && BN % (NW * 8) == 0, "staging");
    constexpr int FM = WM / 16, FN = WN / 16;
    constexpr int IA = BM * 8 / (NW * 64), IB = BN * 8 / (NW * 64);
    constexpr int RA = BM / NW, RB = BN / NW;   // rows staged per wave

    __shared__ bf16x8 As[BM][8];
    __shared__ bf16x8 Bs[BN][8];
    const int tid = threadIdx.x;
    const int l   = tid & 63;
    const int w   = tid >> 6;
    const int wm  = w / (BN / WN), wn = w % (BN / WN);

    // bijective XCD swizzle of the flattened block id
    const int gx = gridDim.x;
    const int bid = blockIdx.y * gx + blockIdx.x;
    const int nwg = gx * gridDim.y;
    const int qq = nwg >> 3, rr = nwg & 7, xcd = bid & 7, loc = bid >> 3;
    const int swz = (xcd < rr ? xcd * (qq + 1) : rr * (qq + 1) + (xcd - rr) * qq) + loc;
    const int brow = (swz / gx) * BM, bcol = (swz % gx) * BN;

    const int lr = l >> 3;            // row within 8-row staging segment
    const int ls = (l & 7) ^ lr;      // pre-swizzled source slot
    const ushort* Ab = A  + (size_t)(brow + w * RA + lr) * lda + ls * 8;
    const ushort* Bb = BT + (size_t)(bcol + w * RB + lr) * ldb + ls * 8;

    f32x4 acc[FM][FN];
#pragma unroll
    for (int i = 0; i < FM; ++i)
#pragma unroll
        for (int j = 0; j < FN; ++j) acc[i][j] = (f32x4)0.f;

    for (int k0 = 0; k0 < K; k0 += 64) {
#pragma unroll
        for (int i = 0; i < IA; ++i)
            __builtin_amdgcn_global_load_lds(
                (const __attribute__((address_space(1))) void*)(Ab + (size_t)(i * 8) * lda + k0),
                (__attribute__((address_space(3))) void*)&As[w * RA + i * 8][0],
                16, 0, 0);
#pragma unroll
        for (int i = 0; i < IB; ++i)
            __builtin_amdgcn_global_load_lds(
                (const __attribute__((address_space(1))) void*)(Bb + (size_t)(i * 8) * ldb + k0),
                (__attribute__((address_space(3))) void*)&Bs[w * RB + i * 8][0],
                16, 0, 0);
        __syncthreads();
#pragma unroll
        for (int kh = 0; kh < 2; ++kh) {
            const int slot = (kh * 4 + (l >> 4)) ^ (l & 7);
            bf16x8 af[FM], bfr[FN];
#pragma unroll
            for (int mt = 0; mt < FM; ++mt)
                af[mt] = As[wm * WM + mt * 16 + (l & 15)][slot];
#pragma unroll
            for (int nt = 0; nt < FN; ++nt)
                bfr[nt] = Bs[wn * WN + nt * 16 + (l & 15)][slot];
#pragma unroll
            for (int mt = 0; mt < FM; ++mt)
#pragma unroll
                for (int nt = 0; nt < FN; ++nt)
                    acc[mt][nt] = __builtin_amdgcn_mfma_f32_16x16x32_bf16(
                        af[mt], bfr[nt], acc[mt][nt], 0, 0, 0);
        }
        __syncthreads();
    }

    const int cr = (l >> 4) * 4, cc = l & 15;
#pragma unroll
    for (int mt = 0; mt < FM; ++mt) {
#pragma unroll
        for (int nt = 0; nt < FN; ++nt) {
            const int gc = bcol + wn * WN + nt * 16 + cc;
            const float bv = bias ? bias[gc] : 0.f;
#pragma unroll
            for (int r = 0; r < 4; ++r) {
                const size_t gr = (size_t)brow + wm * WM + mt * 16 + cr + r;
                float v = acc[mt][nt][r] * scale + bv;
                if (GELU) v = 0.5f * v * (1.f + erff(v * 0.70710678118654752f));
                if (res) v += res[gr * ldr + gc];
                if (OUTBF) ((ushort*)Cp)[gr * ldc + gc] = f2bf(v);
                else       ((float*)Cp)[gr * ldc + gc]  = v;
            }
        }
    }
}

// ---------------------------------------------------------------------------
// Layer-0 attend (bf16 kv in, bf16 o out). One block per bt; wave h = head h.
// Lane layout: dg = l&7 (8-d slice), mg = l>>3 (token within group of 8).
// ---------------------------------------------------------------------------
__global__ __launch_bounds__(512) void attend0_k(
    const ushort* __restrict__ kv, const float* __restrict__ emb,
    const int* __restrict__ targets, ushort* __restrict__ o)
{
    const int bt = blockIdx.x;
    const int l  = threadIdx.x & 63;
    const int h  = threadIdx.x >> 6;
    const int dg = l & 7, mg = l >> 3;
    const int t = targets[bt];

    const float4* qp = reinterpret_cast<const float4*>(emb + t * EDIM + h * 64 + dg * 8);
    float4 q0 = qp[0], q1 = qp[1];
    const float ql[8] = {q0.x, q0.y, q0.z, q0.w, q1.x, q1.y, q1.z, q1.w};

    const ushort* base = kv + (size_t)bt * KVW + h * 64 + dg * 8;

    float dts[2];
#pragma unroll
    for (int g = 0; g < 2; ++g) {
        uint4 kb = *reinterpret_cast<const uint4*>(base + (size_t)(g * 8 + mg) * EDIM);
        const ushort* u = reinterpret_cast<const ushort*>(&kb);
        float p = 0.f;
#pragma unroll
        for (int j = 0; j < 8; ++j) p = fmaf(ql[j], bf2f(u[j]), p);
        p += __shfl_xor(p, 1, 64);
        p += __shfl_xor(p, 2, 64);
        p += __shfl_xor(p, 4, 64);
        dts[g] = p * 0.125f;   // SCALE = 64^-0.5
    }
    float mx = fmaxf(dts[0], dts[1]);
#pragma unroll
    for (int off = 8; off < 64; off <<= 1) mx = fmaxf(mx, __shfl_xor(mx, off, 64));
    float e = expf(dts[0] - mx) + expf(dts[1] - mx);
#pragma unroll
    for (int off = 8; off < 64; off <<= 1) e += __shfl_xor(e, off, 64);
    const float lse = mx + logf(e);
    const float a0 = dts[0] - lse, a1 = dts[1] - lse;

    uint4 v0 = *reinterpret_cast<const uint4*>(base + ENW + (size_t)mg * EDIM);
    uint4 v1 = *reinterpret_cast<const uint4*>(base + ENW + (size_t)(8 + mg) * EDIM);
    const ushort* u0 = reinterpret_cast<const ushort*>(&v0);
    const ushort* u1 = reinterpret_cast<const ushort*>(&v1);
    float acc[8];
#pragma unroll
    for (int j = 0; j < 8; ++j)
        acc[j] = a0 * bf2f(u0[j]) + a1 * bf2f(u1[j]);
#pragma unroll
    for (int off = 8; off < 64; off <<= 1)
#pragma unroll
        for (int j = 0; j < 8; ++j) acc[j] += __shfl_xor(acc[j], off, 64);

    if (mg == 0) {
        uint4 pk;
        pk.x = f2bf(acc[0]) | ((unsigned)f2bf(acc[1]) << 16);
        pk.y = f2bf(acc[2]) | ((unsigned)f2bf(acc[3]) << 16);
        pk.z = f2bf(acc[4]) | ((unsigned)f2bf(acc[5]) << 16);
        pk.w = f2bf(acc[6]) | ((unsigned)f2bf(acc[7]) << 16);
        *reinterpret_cast<uint4*>(o + (size_t)bt * EDIM + h * 64 + dg * 8) = pk;
    }
}

// ---------------------------------------------------------------------------
// Row LayerNorm over E=512: one wave per row; emits f32 AND bf16.
// ---------------------------------------------------------------------------
__global__ __launch_bounds__(256) void ln_k(
    const float* __restrict__ x, const float* __restrict__ g,
    const float* __restrict__ b, float* __restrict__ y,
    ushort* __restrict__ yb)
{
    const int row = blockIdx.x * 4 + (threadIdx.x >> 6);
    const int lane = threadIdx.x & 63;
    const float* xr = x + (size_t)row * EDIM + lane * 8;
    float4 a0 = *reinterpret_cast<const float4*>(xr);
    float4 a1 = *reinterpret_cast<const float4*>(xr + 4);
    float v[8] = {a0.x, a0.y, a0.z, a0.w, a1.x, a1.y, a1.z, a1.w};

    float s = 0.f;
#pragma unroll
    for (int j = 0; j < 8; ++j) s += v[j];
#pragma unroll
    for (int off = 32; off; off >>= 1) s += __shfl_xor(s, off, 64);
    const float m = s * (1.f / 512.f);

    float q = 0.f;
#pragma unroll
    for (int j = 0; j < 8; ++j) { float d = v[j] - m; q = fmaf(d, d, q); }
#pragma unroll
    for (int off = 32; off; off >>= 1) q += __shfl_xor(q, off, 64);
    const float inv = rsqrtf(q * (1.f / 512.f) + 1e-5f);

    const int c = lane * 8;
    float4 g0 = *reinterpret_cast<const float4*>(g + c);
    float4 g1 = *reinterpret_cast<const float4*>(g + c + 4);
    float4 b0 = *reinterpret_cast<const float4*>(b + c);
    float4 b1 = *reinterpret_cast<const float4*>(b + c + 4);
    float gg[8] = {g0.x, g0.y, g0.z, g0.w, g1.x, g1.y, g1.z, g1.w};
    float bb[8] = {b0.x, b0.y, b0.z, b0.w, b1.x, b1.y, b1.z, b1.w};
    float out[8];
#pragma unroll
    for (int j = 0; j < 8; ++j) out[j] = (v[j] - m) * inv * gg[j] + bb[j];
    float* yr = y + (size_t)row * EDIM + c;
    *reinterpret_cast<float4*>(yr) = make_float4(out[0], out[1], out[2], out[3]);
    *reinterpret_cast<float4*>(yr + 4) = make_float4(out[4], out[5], out[6], out[7]);
    uint4 p;
    p.x = f2bf(out[0]) | ((unsigned)f2bf(out[1]) << 16);
    p.y = f2bf(out[2]) | ((unsigned)f2bf(out[3]) << 16);
    p.z = f2bf(out[4]) | ((unsigned)f2bf(out[5]) << 16);
    p.w = f2bf(out[6]) | ((unsigned)f2bf(out[7]) << 16);
    *reinterpret_cast<uint4*>(yb + (size_t)row * EDIM + c) = p;
}

// out[row] = x[row,:] . Wm + bm
__global__ __launch_bounds__(256) void final_k(
    const float* __restrict__ x, const float* __restrict__ Wm,
    const float* __restrict__ bm, float* __restrict__ out)
{
    const int row = blockIdx.x * 4 + (threadIdx.x >> 6);
    const int lane = threadIdx.x & 63;
    const float* xr = x + (size_t)row * EDIM + lane * 8;
    const float* wr = Wm + lane * 8;
    float s = 0.f;
#pragma unroll
    for (int j = 0; j < 8; ++j) s = fmaf(xr[j], wr[j], s);
#pragma unroll
    for (int off = 32; off; off >>= 1) s += __shfl_xor(s, off, 64);
    if (lane == 0) out[row] = s + bm[0];
}

// ---------------------------------------------------------------------------
extern "C" void kernel_launch(void* const* d_in, const int* in_sizes, int n_in,
                              void* d_out, int out_size, void* d_ws, size_t ws_size,
                              hipStream_t stream)
{
    (void)in_sizes; (void)n_in; (void)out_size;
    const float* features = (const float*)d_in[0];
    const int*   targets  = (const int*)d_in[1];
    const float* emb      = (const float*)d_in[2];
    const float* Wf       = (const float*)d_in[3];
    const float* bfv      = (const float*)d_in[4];
    const float* a0Wo     = (const float*)d_in[5];
    const float* a0bo     = (const float*)d_in[6];
    const float* Wm       = (const float*)d_in[7];
    const float* bm       = (const float*)d_in[8];
    const float *ffg[3], *ffb[3], *W1[3], *b1[3], *W2[3], *b2[3];
    for (int i = 0; i < 3; ++i) {
        ffg[i] = (const float*)d_in[9 + 6 * i];
        ffb[i] = (const float*)d_in[10 + 6 * i];
        W1[i]  = (const float*)d_in[11 + 6 * i];
        b1[i]  = (const float*)d_in[12 + 6 * i];
        W2[i]  = (const float*)d_in[13 + 6 * i];
        b2[i]  = (const float*)d_in[14 + 6 * i];
    }
    const float *ag[2], *abp[2], *aWqkv[2], *aWo[2], *abo[2];
    for (int i = 0; i < 2; ++i) {
        ag[i]    = (const float*)d_in[27 + 5 * i];
        abp[i]   = (const float*)d_in[28 + 5 * i];
        aWqkv[i] = (const float*)d_in[29 + 5 * i];
        aWo[i]   = (const float*)d_in[30 + 5 * i];
        abo[i]   = (const float*)d_in[31 + 5 * i];
    }

    // ---- workspace carve-up ----
    char* wsc = (char*)d_ws;
    auto alloc = [&](size_t bytes) { char* p = wsc; wsc += bytes; return p; };
    ushort* WfT   = (ushort*)alloc((size_t)KVW * INP * 2);       // 50.3 MB
    ushort* a0WoT = (ushort*)alloc((size_t)EDIM * EDIM * 2);
    ushort *W1T[3], *W2T[3], *WqkvT[2], *WoT[2];
    for (int i = 0; i < 3; ++i) {
        W1T[i] = (ushort*)alloc((size_t)FFH * EDIM * 2);
        W2T[i] = (ushort*)alloc((size_t)EDIM * FFH * 2);
    }
    for (int i = 0; i < 2; ++i) {
        WqkvT[i] = (ushort*)alloc((size_t)EDIM * EDIM * 2);
        WoT[i]   = (ushort*)alloc((size_t)EDIM * EDIM * 2);
    }
    ushort* featb = (ushort*)alloc((size_t)BTOT * INP * 2);      // 12.6 MB
    ushort* o_b   = (ushort*)alloc((size_t)BTOT * EDIM * 2);     // 4.2 MB
    float*  x     = (float*) alloc((size_t)BTOT * EDIM * 4);     // 8.4 MB
    float*  xln   = (float*) alloc((size_t)BTOT * EDIM * 4);
    ushort* xlnb  = (ushort*)alloc((size_t)BTOT * EDIM * 2);
    ushort* hb    = (ushort*)alloc((size_t)BTOT * FFH * 2);      // 8.4 MB
    const size_t fixed = (size_t)(wsc - (char*)d_ws);
    int CB = BTOT;
    while (CB > 256 && fixed + (size_t)CB * KVW * 2 > ws_size) CB >>= 1;
    ushort* kvb = (ushort*)alloc((size_t)CB * KVW * 2);

    const dim3 blk(256, 1, 1);

    // ---- prep: bf16 conversions / weight transposes ----
    conv_bf16_k<<<(BTOT * INP / 8 + 255) / 256, blk, 0, stream>>>(
        features, featb, BTOT * INP / 8);
    transpose_bf16_k<<<dim3(KVW / 64, INP / 64), blk, 0, stream>>>(
        Wf, KVW, 0, INP, WfT);
    transpose_bf16_k<<<dim3(8, 8), blk, 0, stream>>>(a0Wo, EDIM, 0, EDIM, a0WoT);
    for (int i = 0; i < 3; ++i) {
        transpose_bf16_k<<<dim3(16, 8), blk, 0, stream>>>(W1[i], FFH, 0, EDIM, W1T[i]);
        transpose_bf16_k<<<dim3(8, 16), blk, 0, stream>>>(W2[i], EDIM, 0, FFH, W2T[i]);
    }
    for (int i = 0; i < 2; ++i) {
        transpose_bf16_k<<<dim3(8, 8), blk, 0, stream>>>(aWqkv[i], 3 * EDIM, 2 * EDIM,
                                                         EDIM, WqkvT[i]);
        transpose_bf16_k<<<dim3(8, 8), blk, 0, stream>>>(aWo[i], EDIM, 0, EDIM, WoT[i]);
    }

    // ---- layer 0: kv = f@Wf+bf (bf16 out, chunked), attend0, @Wo+bo ----
    for (int c0 = 0; c0 < BTOT; c0 += CB) {
        gemm_mfma_k<128, 128, 64, 64, 4, false, true>
            <<<dim3(KVW / 128, CB / 128), blk, 0, stream>>>(
            featb + (size_t)c0 * INP, INP, WfT, INP, kvb, KVW, INP,
            bfv, nullptr, 0, 1.f);
        attend0_k<<<CB, 512, 0, stream>>>(kvb, emb, targets + c0,
                                          o_b + (size_t)c0 * EDIM);
    }
    gemm_mfma_k<64, 128, 32, 64, 4, false, false>
        <<<dim3(EDIM / 128, BTOT / 64), blk, 0, stream>>>(
        o_b, EDIM, a0WoT, EDIM, x, EDIM, EDIM, a0bo, nullptr, 0, 1.f);

    // log_softmax of 16 equal logits = -ln16; o = -16*ln16 * v.
    const float CATT = -44.36141955583650f;

    auto ln = [&](const float* g, const float* b) {
        ln_k<<<BTOT / 4, blk, 0, stream>>>(x, g, b, xln, xlnb);
    };
    auto ff = [&](int i) {
        ln(ffg[i], ffb[i]);
        gemm_mfma_k<64, 128, 32, 64, 4, true, true>
            <<<dim3(FFH / 128, BTOT / 64), blk, 0, stream>>>(
            xlnb, EDIM, W1T[i], EDIM, hb, FFH, EDIM, b1[i], nullptr, 0, 1.f);
        gemm_mfma_k<64, 128, 32, 64, 4, false, false>
            <<<dim3(EDIM / 128, BTOT / 64), blk, 0, stream>>>(
            hb, FFH, W2T[i], FFH, x, EDIM, FFH, b2[i], xln, EDIM, 1.f);
    };
    auto attn = [&](int i) {
        ln(ag[i], abp[i]);
        gemm_mfma_k<64, 128, 32, 64, 4, false, true>
            <<<dim3(EDIM / 128, BTOT / 64), blk, 0, stream>>>(
            xlnb, EDIM, WqkvT[i], EDIM, o_b, EDIM, EDIM, nullptr, nullptr, 0, 1.f);
        gemm_mfma_k<64, 128, 32, 64, 4, false, false>
            <<<dim3(EDIM / 128, BTOT / 64), blk, 0, stream>>>(
            o_b, EDIM, WoT[i], EDIM, x, EDIM, EDIM, abo[i], xln, EDIM, CATT);
    };

    ff(0);
    attn(0);
    ff(1);
    attn(1);
    ff(2);

    final_k<<<BTOT / 4, blk, 0, stream>>>(x, Wm, bm, (float*)d_out);
}

// Round 4
// 541.784 us; speedup vs baseline: 5.4953x; 1.0950x over previous
//
#include <hip/hip_runtime.h>
#include <math.h>

// MixedHead: B=16,T=256 -> BT=4096; INP=1536; E=512; H=8; N=16; D=64.
#define BTOT 4096
#define INP  1536
#define EDIM 512
#define NTOK 16
#define KVW  16384   // 2*E*N
#define ENW  8192    // E*N
#define FFH  1024    // 2*E

typedef __attribute__((ext_vector_type(8))) __bf16 bf16x8;
typedef __attribute__((ext_vector_type(4))) float f32x4;

__device__ __forceinline__ ushort f2bf(float f) {
    union { float f; unsigned u; } v; v.f = f;
    unsigned r = v.u + 0x7fffu + ((v.u >> 16) & 1u);
    return (ushort)(r >> 16);
}
__device__ __forceinline__ float bf2f(ushort h) {
    union { unsigned u; float f; } v; v.u = ((unsigned)h) << 16;
    return v.f;
}

// ---------------------------------------------------------------------------
// Transpose f32 [R][ld] (cols c0..) -> bf16 [C][R].  Grid (C/64, R/64).
// ---------------------------------------------------------------------------
__device__ __forceinline__ void transpose_body(
    const float* in, int ld, int c0, int R, ushort* out,
    int bx, int by, int tid)
{
    __shared__ float t[64][65];
    const int bc = bx * 64 + c0;
    const int br = by * 64;
#pragma unroll
    for (int it = 0; it < 16; ++it) {
        int idx = tid + it * 256;
        int r = idx >> 6, c = idx & 63;
        t[r][c] = in[(size_t)(br + r) * ld + bc + c];
    }
    __syncthreads();
    const int C0 = bx * 64;
#pragma unroll
    for (int it = 0; it < 4; ++it) {
        int idx = tid + it * 256;          // 1024 = 64 cols x 16 row-quads
        int cc = idx >> 4, rp = idx & 15;
        uint2 w2;
        w2.x = f2bf(t[4 * rp + 0][cc]) | ((unsigned)f2bf(t[4 * rp + 1][cc]) << 16);
        w2.y = f2bf(t[4 * rp + 2][cc]) | ((unsigned)f2bf(t[4 * rp + 3][cc]) << 16);
        *reinterpret_cast<uint2*>(out + (size_t)(C0 + cc) * R + br + 4 * rp) = w2;
    }
}

__global__ __launch_bounds__(256) void transpose_bf16_k(
    const float* __restrict__ in, int ld, int c0, int R,
    ushort* __restrict__ out)
{
    transpose_body(in, ld, c0, R, out, blockIdx.x, blockIdx.y, threadIdx.x);
}

struct TJob { const float* in; ushort* out; int ld, c0, R, gbx, gby; };
struct TJobs { TJob j[9]; };

__global__ __launch_bounds__(256) void transpose_batch_k(TJobs jobs)
{
    TJob jb = jobs.j[blockIdx.z];
    if ((int)blockIdx.x >= jb.gbx || (int)blockIdx.y >= jb.gby) return;
    transpose_body(jb.in, jb.ld, jb.c0, jb.R, jb.out,
                   blockIdx.x, blockIdx.y, threadIdx.x);
}

// f32 -> bf16 flat convert, 8 elems/thread.
__global__ __launch_bounds__(256) void conv_bf16_k(
    const float* __restrict__ in, ushort* __restrict__ out, int n8)
{
    int i = blockIdx.x * 256 + threadIdx.x;
    if (i >= n8) return;
    const float4* p = reinterpret_cast<const float4*>(in) + 2 * (size_t)i;
    float4 a = p[0], b = p[1];
    uint4 o;
    o.x = f2bf(a.x) | ((unsigned)f2bf(a.y) << 16);
    o.y = f2bf(a.z) | ((unsigned)f2bf(a.w) << 16);
    o.z = f2bf(b.x) | ((unsigned)f2bf(b.y) << 16);
    o.w = f2bf(b.z) | ((unsigned)f2bf(b.w) << 16);
    reinterpret_cast<uint4*>(out)[i] = o;
}

// Strided bf16 convert of the v-slice of Wqkv: out[k][e] = in[k][1024+e],
// in [512][1536] f32, out [512][512] bf16. grid (128, 2) jobs via blockIdx.y.
__global__ __launch_bounds__(256) void conv_wv_k(
    const float* __restrict__ s0, const float* __restrict__ s1,
    ushort* __restrict__ d0, ushort* __restrict__ d1)
{
    const float* src = blockIdx.y ? s1 : s0;
    ushort* dst = blockIdx.y ? d1 : d0;
    int idx = blockIdx.x * 256 + threadIdx.x;   // 32768 total
    int row = idx >> 6, c8 = (idx & 63) * 8;
    const float4* p = reinterpret_cast<const float4*>(
        src + (size_t)row * (3 * EDIM) + 2 * EDIM + c8);
    float4 a = p[0], b = p[1];
    uint4 o;
    o.x = f2bf(a.x) | ((unsigned)f2bf(a.y) << 16);
    o.y = f2bf(a.z) | ((unsigned)f2bf(a.w) << 16);
    o.z = f2bf(b.x) | ((unsigned)f2bf(b.y) << 16);
    o.w = f2bf(b.z) | ((unsigned)f2bf(b.w) << 16);
    *reinterpret_cast<uint4*>(dst + (size_t)row * EDIM + c8) = o;
}

// ---------------------------------------------------------------------------
// bf16 MFMA GEMM: C[M,N] = epi(scale*A@BT^T + bias [+gelu] [+res])
// A bf16 [M][K] lda=K, BT bf16 [N][K] ldb=K. BMxBN tile, BK=64, NW waves,
// per-wave WMxWN output. LDS [rows][8 x 16B], XOR slot^(row&7); staging via
// global_load_lds with pre-swizzled global source. No XCD swizzle (L3-fit).
// ---------------------------------------------------------------------------
template <int BM, int BN, int WM, int WN, int NW, bool GELU, bool OUTBF>
__global__ __launch_bounds__(NW * 64) void gemm_mfma_k(
    const ushort* __restrict__ A, int lda,
    const ushort* __restrict__ BT, int ldb,
    void* __restrict__ Cp, int ldc, int K,
    const float* __restrict__ bias,
    const float* __restrict__ res, int ldr,
    float scale)
{
    static_assert((BM / WM) * (BN / WN) == NW, "wave grid");
    static_assert(BM % (NW * 8) == 0 && BN % (NW * 8) == 0, "staging");
    constexpr int FM = WM / 16, FN = WN / 16;
    constexpr int IA = BM * 8 / (NW * 64), IB = BN * 8 / (NW * 64);
    constexpr int RA = BM / NW, RB = BN / NW;   // rows staged per wave

    __shared__ bf16x8 As[BM][8];
    __shared__ bf16x8 Bs[BN][8];
    const int tid = threadIdx.x;
    const int l   = tid & 63;
    const int w   = tid >> 6;
    const int wm  = w / (BN / WN), wn = w % (BN / WN);
    const int brow = blockIdx.y * BM, bcol = blockIdx.x * BN;

    const int lr = l >> 3;            // row within 8-row staging segment
    const int ls = (l & 7) ^ lr;      // pre-swizzled source slot
    const ushort* Ab = A  + (size_t)(brow + w * RA + lr) * lda + ls * 8;
    const ushort* Bb = BT + (size_t)(bcol + w * RB + lr) * ldb + ls * 8;

    f32x4 acc[FM][FN];
#pragma unroll
    for (int i = 0; i < FM; ++i)
#pragma unroll
        for (int j = 0; j < FN; ++j) acc[i][j] = (f32x4)0.f;

    for (int k0 = 0; k0 < K; k0 += 64) {
#pragma unroll
        for (int i = 0; i < IA; ++i)
            __builtin_amdgcn_global_load_lds(
                (const __attribute__((address_space(1))) void*)(Ab + (size_t)(i * 8) * lda + k0),
                (__attribute__((address_space(3))) void*)&As[w * RA + i * 8][0],
                16, 0, 0);
#pragma unroll
        for (int i = 0; i < IB; ++i)
            __builtin_amdgcn_global_load_lds(
                (const __attribute__((address_space(1))) void*)(Bb + (size_t)(i * 8) * ldb + k0),
                (__attribute__((address_space(3))) void*)&Bs[w * RB + i * 8][0],
                16, 0, 0);
        __syncthreads();
#pragma unroll
        for (int kh = 0; kh < 2; ++kh) {
            const int slot = (kh * 4 + (l >> 4)) ^ (l & 7);
            bf16x8 af[FM], bfr[FN];
#pragma unroll
            for (int mt = 0; mt < FM; ++mt)
                af[mt] = As[wm * WM + mt * 16 + (l & 15)][slot];
#pragma unroll
            for (int nt = 0; nt < FN; ++nt)
                bfr[nt] = Bs[wn * WN + nt * 16 + (l & 15)][slot];
#pragma unroll
            for (int mt = 0; mt < FM; ++mt)
#pragma unroll
                for (int nt = 0; nt < FN; ++nt)
                    acc[mt][nt] = __builtin_amdgcn_mfma_f32_16x16x32_bf16(
                        af[mt], bfr[nt], acc[mt][nt], 0, 0, 0);
        }
        __syncthreads();
    }

    const int cr = (l >> 4) * 4, cc = l & 15;
#pragma unroll
    for (int mt = 0; mt < FM; ++mt) {
#pragma unroll
        for (int nt = 0; nt < FN; ++nt) {
            const int gc = bcol + wn * WN + nt * 16 + cc;
            const float bv = bias ? bias[gc] : 0.f;
#pragma unroll
            for (int r = 0; r < 4; ++r) {
                const size_t gr = (size_t)brow + wm * WM + mt * 16 + cr + r;
                float v = acc[mt][nt][r] * scale + bv;
                if (GELU) v = 0.5f * v * (1.f + erff(v * 0.70710678118654752f));
                if (res) v += res[gr * ldr + gc];
                if (OUTBF) ((ushort*)Cp)[gr * ldc + gc] = f2bf(v);
                else       ((float*)Cp)[gr * ldc + gc]  = v;
            }
        }
    }
}

// ---------------------------------------------------------------------------
// Layer-0 attend (bf16 kv in, bf16 o out). One block per bt; wave h = head h.
// Lane layout: dg = l&7 (8-d slice), mg = l>>3 (token within group of 8).
// ---------------------------------------------------------------------------
__global__ __launch_bounds__(512) void attend0_k(
    const ushort* __restrict__ kv, const float* __restrict__ emb,
    const int* __restrict__ targets, ushort* __restrict__ o)
{
    const int bt = blockIdx.x;
    const int l  = threadIdx.x & 63;
    const int h  = threadIdx.x >> 6;
    const int dg = l & 7, mg = l >> 3;
    const int t = targets[bt];

    const float4* qp = reinterpret_cast<const float4*>(emb + t * EDIM + h * 64 + dg * 8);
    float4 q0 = qp[0], q1 = qp[1];
    const float ql[8] = {q0.x, q0.y, q0.z, q0.w, q1.x, q1.y, q1.z, q1.w};

    const ushort* base = kv + (size_t)bt * KVW + h * 64 + dg * 8;

    float dts[2];
#pragma unroll
    for (int g = 0; g < 2; ++g) {
        uint4 kb = *reinterpret_cast<const uint4*>(base + (size_t)(g * 8 + mg) * EDIM);
        const ushort* u = reinterpret_cast<const ushort*>(&kb);
        float p = 0.f;
#pragma unroll
        for (int j = 0; j < 8; ++j) p = fmaf(ql[j], bf2f(u[j]), p);
        p += __shfl_xor(p, 1, 64);
        p += __shfl_xor(p, 2, 64);
        p += __shfl_xor(p, 4, 64);
        dts[g] = p * 0.125f;   // SCALE = 64^-0.5
    }
    float mx = fmaxf(dts[0], dts[1]);
#pragma unroll
    for (int off = 8; off < 64; off <<= 1) mx = fmaxf(mx, __shfl_xor(mx, off, 64));
    float e = expf(dts[0] - mx) + expf(dts[1] - mx);
#pragma unroll
    for (int off = 8; off < 64; off <<= 1) e += __shfl_xor(e, off, 64);
    const float lse = mx + logf(e);
    const float a0 = dts[0] - lse, a1 = dts[1] - lse;

    uint4 v0 = *reinterpret_cast<const uint4*>(base + ENW + (size_t)mg * EDIM);
    uint4 v1 = *reinterpret_cast<const uint4*>(base + ENW + (size_t)(8 + mg) * EDIM);
    const ushort* u0 = reinterpret_cast<const ushort*>(&v0);
    const ushort* u1 = reinterpret_cast<const ushort*>(&v1);
    float acc[8];
#pragma unroll
    for (int j = 0; j < 8; ++j)
        acc[j] = a0 * bf2f(u0[j]) + a1 * bf2f(u1[j]);
#pragma unroll
    for (int off = 8; off < 64; off <<= 1)
#pragma unroll
        for (int j = 0; j < 8; ++j) acc[j] += __shfl_xor(acc[j], off, 64);

    if (mg == 0) {
        uint4 pk;
        pk.x = f2bf(acc[0]) | ((unsigned)f2bf(acc[1]) << 16);
        pk.y = f2bf(acc[2]) | ((unsigned)f2bf(acc[3]) << 16);
        pk.z = f2bf(acc[4]) | ((unsigned)f2bf(acc[5]) << 16);
        pk.w = f2bf(acc[6]) | ((unsigned)f2bf(acc[7]) << 16);
        *reinterpret_cast<uint4*>(o + (size_t)bt * EDIM + h * 64 + dg * 8) = pk;
    }
}

// ---------------------------------------------------------------------------
// Row LayerNorm over E=512: one wave per row; emits f32 AND bf16.
// ---------------------------------------------------------------------------
__global__ __launch_bounds__(256) void ln_k(
    const float* __restrict__ x, const float* __restrict__ g,
    const float* __restrict__ b, float* __restrict__ y,
    ushort* __restrict__ yb)
{
    const int row = blockIdx.x * 4 + (threadIdx.x >> 6);
    const int lane = threadIdx.x & 63;
    const float* xr = x + (size_t)row * EDIM + lane * 8;
    float4 a0 = *reinterpret_cast<const float4*>(xr);
    float4 a1 = *reinterpret_cast<const float4*>(xr + 4);
    float v[8] = {a0.x, a0.y, a0.z, a0.w, a1.x, a1.y, a1.z, a1.w};

    float s = 0.f;
#pragma unroll
    for (int j = 0; j < 8; ++j) s += v[j];
#pragma unroll
    for (int off = 32; off; off >>= 1) s += __shfl_xor(s, off, 64);
    const float m = s * (1.f / 512.f);

    float q = 0.f;
#pragma unroll
    for (int j = 0; j < 8; ++j) { float d = v[j] - m; q = fmaf(d, d, q); }
#pragma unroll
    for (int off = 32; off; off >>= 1) q += __shfl_xor(q, off, 64);
    const float inv = rsqrtf(q * (1.f / 512.f) + 1e-5f);

    const int c = lane * 8;
    float4 g0 = *reinterpret_cast<const float4*>(g + c);
    float4 g1 = *reinterpret_cast<const float4*>(g + c + 4);
    float4 b0 = *reinterpret_cast<const float4*>(b + c);
    float4 b1 = *reinterpret_cast<const float4*>(b + c + 4);
    float gg[8] = {g0.x, g0.y, g0.z, g0.w, g1.x, g1.y, g1.z, g1.w};
    float bb[8] = {b0.x, b0.y, b0.z, b0.w, b1.x, b1.y, b1.z, b1.w};
    float out[8];
#pragma unroll
    for (int j = 0; j < 8; ++j) out[j] = (v[j] - m) * inv * gg[j] + bb[j];
    float* yr = y + (size_t)row * EDIM + c;
    *reinterpret_cast<float4*>(yr) = make_float4(out[0], out[1], out[2], out[3]);
    *reinterpret_cast<float4*>(yr + 4) = make_float4(out[4], out[5], out[6], out[7]);
    uint4 p;
    p.x = f2bf(out[0]) | ((unsigned)f2bf(out[1]) << 16);
    p.y = f2bf(out[2]) | ((unsigned)f2bf(out[3]) << 16);
    p.z = f2bf(out[4]) | ((unsigned)f2bf(out[5]) << 16);
    p.w = f2bf(out[6]) | ((unsigned)f2bf(out[7]) << 16);
    *reinterpret_cast<uint4*>(yb + (size_t)row * EDIM + c) = p;
}

// out[row] = x[row,:] . Wm + bm
__global__ __launch_bounds__(256) void final_k(
    const float* __restrict__ x, const float* __restrict__ Wm,
    const float* __restrict__ bm, float* __restrict__ out)
{
    const int row = blockIdx.x * 4 + (threadIdx.x >> 6);
    const int lane = threadIdx.x & 63;
    const float* xr = x + (size_t)row * EDIM + lane * 8;
    const float* wr = Wm + lane * 8;
    float s = 0.f;
#pragma unroll
    for (int j = 0; j < 8; ++j) s = fmaf(xr[j], wr[j], s);
#pragma unroll
    for (int off = 32; off; off >>= 1) s += __shfl_xor(s, off, 64);
    if (lane == 0) out[row] = s + bm[0];
}

// ---------------------------------------------------------------------------
extern "C" void kernel_launch(void* const* d_in, const int* in_sizes, int n_in,
                              void* d_out, int out_size, void* d_ws, size_t ws_size,
                              hipStream_t stream)
{
    (void)in_sizes; (void)n_in; (void)out_size;
    const float* features = (const float*)d_in[0];
    const int*   targets  = (const int*)d_in[1];
    const float* emb      = (const float*)d_in[2];
    const float* Wf       = (const float*)d_in[3];
    const float* bfv      = (const float*)d_in[4];
    const float* a0Wo     = (const float*)d_in[5];
    const float* a0bo     = (const float*)d_in[6];
    const float* Wm       = (const float*)d_in[7];
    const float* bm       = (const float*)d_in[8];
    const float *ffg[3], *ffb[3], *W1[3], *b1[3], *W2[3], *b2[3];
    for (int i = 0; i < 3; ++i) {
        ffg[i] = (const float*)d_in[9 + 6 * i];
        ffb[i] = (const float*)d_in[10 + 6 * i];
        W1[i]  = (const float*)d_in[11 + 6 * i];
        b1[i]  = (const float*)d_in[12 + 6 * i];
        W2[i]  = (const float*)d_in[13 + 6 * i];
        b2[i]  = (const float*)d_in[14 + 6 * i];
    }
    const float *ag[2], *abp[2], *aWqkv[2], *aWo[2], *abo[2];
    for (int i = 0; i < 2; ++i) {
        ag[i]    = (const float*)d_in[27 + 5 * i];
        abp[i]   = (const float*)d_in[28 + 5 * i];
        aWqkv[i] = (const float*)d_in[29 + 5 * i];
        aWo[i]   = (const float*)d_in[30 + 5 * i];
        abo[i]   = (const float*)d_in[31 + 5 * i];
    }

    // ---- workspace carve-up ----
    char* wsc = (char*)d_ws;
    auto alloc = [&](size_t bytes) { char* p = wsc; wsc += bytes; return p; };
    ushort* WfT   = (ushort*)alloc((size_t)KVW * INP * 2);       // 50.3 MB
    ushort* a0WoT = (ushort*)alloc((size_t)EDIM * EDIM * 2);
    ushort *W1T[3], *W2T[3], *WoT[2], *Wv_bf[2], *WcombT[2];
    for (int i = 0; i < 3; ++i) {
        W1T[i] = (ushort*)alloc((size_t)FFH * EDIM * 2);
        W2T[i] = (ushort*)alloc((size_t)EDIM * FFH * 2);
    }
    for (int i = 0; i < 2; ++i) {
        WoT[i]    = (ushort*)alloc((size_t)EDIM * EDIM * 2);
        Wv_bf[i]  = (ushort*)alloc((size_t)EDIM * EDIM * 2);
        WcombT[i] = (ushort*)alloc((size_t)EDIM * EDIM * 2);
    }
    ushort* featb = (ushort*)alloc((size_t)BTOT * INP * 2);      // 12.6 MB
    ushort* o_b   = (ushort*)alloc((size_t)BTOT * EDIM * 2);     // 4.2 MB
    float*  x     = (float*) alloc((size_t)BTOT * EDIM * 4);     // 8.4 MB
    float*  xln   = (float*) alloc((size_t)BTOT * EDIM * 4);
    ushort* xlnb  = (ushort*)alloc((size_t)BTOT * EDIM * 2);
    ushort* hb    = (ushort*)alloc((size_t)BTOT * FFH * 2);      // 8.4 MB
    const size_t fixed = (size_t)(wsc - (char*)d_ws);
    int CB = BTOT;
    while (CB > 256 && fixed + (size_t)CB * KVW * 2 > ws_size) CB >>= 1;
    ushort* kvb = (ushort*)alloc((size_t)CB * KVW * 2);

    const dim3 blk(256, 1, 1);

    // ---- prep: bf16 conversions / weight transposes ----
    conv_bf16_k<<<(BTOT * INP / 8 + 255) / 256, blk, 0, stream>>>(
        features, featb, BTOT * INP / 8);
    transpose_bf16_k<<<dim3(KVW / 64, INP / 64), blk, 0, stream>>>(
        Wf, KVW, 0, INP, WfT);

    TJobs tj;
    tj.j[0] = {a0Wo, a0WoT, EDIM, 0, EDIM, 8, 8};
    for (int i = 0; i < 3; ++i) {
        tj.j[1 + 2 * i] = {W1[i], W1T[i], FFH, 0, EDIM, 16, 8};
        tj.j[2 + 2 * i] = {W2[i], W2T[i], EDIM, 0, FFH, 8, 16};
    }
    tj.j[7] = {aWo[0], WoT[0], EDIM, 0, EDIM, 8, 8};
    tj.j[8] = {aWo[1], WoT[1], EDIM, 0, EDIM, 8, 8};
    transpose_batch_k<<<dim3(16, 16, 9), blk, 0, stream>>>(tj);

    conv_wv_k<<<dim3(128, 2), blk, 0, stream>>>(aWqkv[0], aWqkv[1],
                                                Wv_bf[0], Wv_bf[1]);

    // W_combT = CATT * WoT @ Wv^T  ->  attn layer: x = xln@Wcomb + bo + xln.
    // log_softmax of 16 equal logits = -ln16; o = -16*ln16 * v.
    const float CATT = -44.36141955583650f;
    for (int i = 0; i < 2; ++i)
        gemm_mfma_k<64, 128, 32, 64, 4, false, true>
            <<<dim3(EDIM / 128, EDIM / 64), blk, 0, stream>>>(
            WoT[i], EDIM, Wv_bf[i], EDIM, WcombT[i], EDIM, EDIM,
            nullptr, nullptr, 0, CATT);

    // ---- layer 0: kv = f@Wf+bf (bf16 out, chunked), attend0, @Wo+bo ----
    for (int c0 = 0; c0 < BTOT; c0 += CB) {
        gemm_mfma_k<128, 128, 64, 64, 4, false, true>
            <<<dim3(KVW / 128, CB / 128), blk, 0, stream>>>(
            featb + (size_t)c0 * INP, INP, WfT, INP, kvb, KVW, INP,
            bfv, nullptr, 0, 1.f);
        attend0_k<<<CB, 512, 0, stream>>>(kvb, emb, targets + c0,
                                          o_b + (size_t)c0 * EDIM);
    }
    gemm_mfma_k<64, 128, 32, 64, 4, false, false>
        <<<dim3(EDIM / 128, BTOT / 64), blk, 0, stream>>>(
        o_b, EDIM, a0WoT, EDIM, x, EDIM, EDIM, a0bo, nullptr, 0, 1.f);

    auto ln = [&](const float* g, const float* b) {
        ln_k<<<BTOT / 4, blk, 0, stream>>>(x, g, b, xln, xlnb);
    };
    auto ff = [&](int i) {
        ln(ffg[i], ffb[i]);
        gemm_mfma_k<64, 128, 32, 64, 4, true, true>
            <<<dim3(FFH / 128, BTOT / 64), blk, 0, stream>>>(
            xlnb, EDIM, W1T[i], EDIM, hb, FFH, EDIM, b1[i], nullptr, 0, 1.f);
        gemm_mfma_k<64, 128, 32, 64, 4, false, false>
            <<<dim3(EDIM / 128, BTOT / 64), blk, 0, stream>>>(
            hb, FFH, W2T[i], FFH, x, EDIM, FFH, b2[i], xln, EDIM, 1.f);
    };
    auto attn = [&](int i) {
        ln(ag[i], abp[i]);
        gemm_mfma_k<64, 128, 32, 64, 4, false, false>
            <<<dim3(EDIM / 128, BTOT / 64), blk, 0, stream>>>(
            xlnb, EDIM, WcombT[i], EDIM, x, EDIM, EDIM, abo[i], xln, EDIM, 1.f);
    };

    ff(0);
    attn(0);
    ff(1);
    attn(1);
    ff(2);

    final_k<<<BTOT / 4, blk, 0, stream>>>(x, Wm, bm, (float*)d_out);
}

// Round 5
// 532.666 us; speedup vs baseline: 5.5893x; 1.0171x over previous
//
#include <hip/hip_runtime.h>
#include <math.h>

// MixedHead: B=16,T=256 -> BT=4096; INP=1536; E=512; H=8; N=16; D=64.
#define BTOT 4096
#define INP  1536
#define EDIM 512
#define NTOK 16
#define KVW  16384   // 2*E*N
#define ENW  8192    // E*N
#define FFH  1024    // 2*E
#define NDOT 2048    // 16 targets x 128 (h,m)

typedef __attribute__((ext_vector_type(8))) __bf16 bf16x8;
typedef __attribute__((ext_vector_type(4))) float f32x4;

__device__ __forceinline__ ushort f2bf(float f) {
    union { float f; unsigned u; } v; v.f = f;
    unsigned r = v.u + 0x7fffu + ((v.u >> 16) & 1u);
    return (ushort)(r >> 16);
}
__device__ __forceinline__ float bf2f(ushort h) {
    union { unsigned u; float f; } v; v.u = ((unsigned)h) << 16;
    return v.f;
}

// ---------------------------------------------------------------------------
// Transpose f32 [R][ld] (cols c0..) -> bf16 [C][R].  Grid (C/64, R/64).
// ---------------------------------------------------------------------------
__device__ __forceinline__ void transpose_body(
    const float* in, int ld, int c0, int R, ushort* out,
    int bx, int by, int tid)
{
    __shared__ float t[64][65];
    const int bc = bx * 64 + c0;
    const int br = by * 64;
#pragma unroll
    for (int it = 0; it < 16; ++it) {
        int idx = tid + it * 256;
        int r = idx >> 6, c = idx & 63;
        t[r][c] = in[(size_t)(br + r) * ld + bc + c];
    }
    __syncthreads();
    const int C0 = bx * 64;
#pragma unroll
    for (int it = 0; it < 4; ++it) {
        int idx = tid + it * 256;          // 1024 = 64 cols x 16 row-quads
        int cc = idx >> 4, rp = idx & 15;
        uint2 w2;
        w2.x = f2bf(t[4 * rp + 0][cc]) | ((unsigned)f2bf(t[4 * rp + 1][cc]) << 16);
        w2.y = f2bf(t[4 * rp + 2][cc]) | ((unsigned)f2bf(t[4 * rp + 3][cc]) << 16);
        *reinterpret_cast<uint2*>(out + (size_t)(C0 + cc) * R + br + 4 * rp) = w2;
    }
}

__global__ __launch_bounds__(256) void transpose_bf16_k(
    const float* __restrict__ in, int ld, int c0, int R,
    ushort* __restrict__ out)
{
    transpose_body(in, ld, c0, R, out, blockIdx.x, blockIdx.y, threadIdx.x);
}

struct TJob { const float* in; ushort* out; int ld, c0, R, gbx, gby; };
struct TJobs { TJob j[9]; };

__global__ __launch_bounds__(256) void transpose_batch_k(TJobs jobs)
{
    TJob jb = jobs.j[blockIdx.z];
    if ((int)blockIdx.x >= jb.gbx || (int)blockIdx.y >= jb.gby) return;
    transpose_body(jb.in, jb.ld, jb.c0, jb.R, jb.out,
                   blockIdx.x, blockIdx.y, threadIdx.x);
}

// f32 -> bf16 flat convert, 8 elems/thread.
__global__ __launch_bounds__(256) void conv_bf16_k(
    const float* __restrict__ in, ushort* __restrict__ out, int n8)
{
    int i = blockIdx.x * 256 + threadIdx.x;
    if (i >= n8) return;
    const float4* p = reinterpret_cast<const float4*>(in) + 2 * (size_t)i;
    float4 a = p[0], b = p[1];
    uint4 o;
    o.x = f2bf(a.x) | ((unsigned)f2bf(a.y) << 16);
    o.y = f2bf(a.z) | ((unsigned)f2bf(a.w) << 16);
    o.z = f2bf(b.x) | ((unsigned)f2bf(b.y) << 16);
    o.w = f2bf(b.z) | ((unsigned)f2bf(b.w) << 16);
    reinterpret_cast<uint4*>(out)[i] = o;
}

// Strided bf16 convert of the v-slice of Wqkv: out[k][e] = in[k][1024+e].
__global__ __launch_bounds__(256) void conv_wv_k(
    const float* __restrict__ s0, const float* __restrict__ s1,
    ushort* __restrict__ d0, ushort* __restrict__ d1)
{
    const float* src = blockIdx.y ? s1 : s0;
    ushort* dst = blockIdx.y ? d1 : d0;
    int idx = blockIdx.x * 256 + threadIdx.x;   // 32768 total
    int row = idx >> 6, c8 = (idx & 63) * 8;
    const float4* p = reinterpret_cast<const float4*>(
        src + (size_t)row * (3 * EDIM) + 2 * EDIM + c8);
    float4 a = p[0], b = p[1];
    uint4 o;
    o.x = f2bf(a.x) | ((unsigned)f2bf(a.y) << 16);
    o.y = f2bf(a.z) | ((unsigned)f2bf(a.w) << 16);
    o.z = f2bf(b.x) | ((unsigned)f2bf(b.y) << 16);
    o.w = f2bf(b.z) | ((unsigned)f2bf(b.w) << 16);
    *reinterpret_cast<uint4*>(dst + (size_t)row * EDIM + c8) = o;
}

// ---------------------------------------------------------------------------
// G projection: BTg[t*128 + h*16 + m][i] = sum_d Wf[i][m*512+h*64+d]*emb[t][h*64+d]
// (bf16), and C0s[n] = 0.125 * sum_d bfv[m*512+h*64+d]*emb[t][h*64+d] (f32).
// Grid: 128 blocks (hm), 256 threads. lane = t(4b) | isub(2b); 16 i per iter.
// ---------------------------------------------------------------------------
__global__ __launch_bounds__(256) void gproj_k(
    const float* __restrict__ Wf, const float* __restrict__ bfv,
    const float* __restrict__ emb, ushort* __restrict__ BTg,
    float* __restrict__ C0s)
{
    const int hm = blockIdx.x;           // h*16 + m
    const int h = hm >> 4, m = hm & 15;
    const int l = threadIdx.x & 63, w = threadIdx.x >> 6;
    const int t = l & 15, isub = l >> 4;
    const int colb = m * 512 + h * 64;

    float4 e[16];
#pragma unroll
    for (int q = 0; q < 16; ++q)
        e[q] = *reinterpret_cast<const float4*>(emb + t * EDIM + h * 64 + q * 4);

    const int n = t * 128 + hm;
    for (int i0 = 0; i0 < INP; i0 += 16) {
        const int i = i0 + w * 4 + isub;
        const float* wr = Wf + (size_t)i * KVW + colb;
        float acc = 0.f;
#pragma unroll
        for (int q = 0; q < 16; ++q) {
            float4 v4 = *reinterpret_cast<const float4*>(wr + q * 4);
            acc = fmaf(v4.x, e[q].x, fmaf(v4.y, e[q].y,
                  fmaf(v4.z, e[q].z, fmaf(v4.w, e[q].w, acc))));
        }
        BTg[(size_t)n * INP + i] = f2bf(acc);
    }
    if (w == 0 && isub == 0) {
        const float* br = bfv + colb;
        float acc = 0.f;
#pragma unroll
        for (int q = 0; q < 16; ++q) {
            float4 v4 = *reinterpret_cast<const float4*>(br + q * 4);
            acc = fmaf(v4.x, e[q].x, fmaf(v4.y, e[q].y,
                  fmaf(v4.z, e[q].z, fmaf(v4.w, e[q].w, acc))));
        }
        C0s[n] = 0.125f * acc;
    }
}

// ---------------------------------------------------------------------------
// bf16 MFMA GEMM: C[M,N] = epi(scale*A@BT^T + bias [+gelu] [+res])
// A bf16 [M][K] lda=K, BT bf16 [N][K] ldb=K. BMxBN tile, BK=64, NW waves,
// per-wave WMxWN output. LDS [rows][8 x 16B], XOR slot^(row&7); staging via
// global_load_lds with pre-swizzled global source. No XCD swizzle (L3-fit).
// ---------------------------------------------------------------------------
template <int BM, int BN, int WM, int WN, int NW, bool GELU, bool OUTBF>
__global__ __launch_bounds__(NW * 64) void gemm_mfma_k(
    const ushort* __restrict__ A, int lda,
    const ushort* __restrict__ BT, int ldb,
    void* __restrict__ Cp, int ldc, int K,
    const float* __restrict__ bias,
    const float* __restrict__ res, int ldr,
    float scale)
{
    static_assert((BM / WM) * (BN / WN) == NW, "wave grid");
    static_assert(BM % (NW * 8) == 0 && BN % (NW * 8) == 0, "staging");
    constexpr int FM = WM / 16, FN = WN / 16;
    constexpr int IA = BM * 8 / (NW * 64), IB = BN * 8 / (NW * 64);
    constexpr int RA = BM / NW, RB = BN / NW;   // rows staged per wave

    __shared__ bf16x8 As[BM][8];
    __shared__ bf16x8 Bs[BN][8];
    const int tid = threadIdx.x;
    const int l   = tid & 63;
    const int w   = tid >> 6;
    const int wm  = w / (BN / WN), wn = w % (BN / WN);
    const int brow = blockIdx.y * BM, bcol = blockIdx.x * BN;

    const int lr = l >> 3;            // row within 8-row staging segment
    const int ls = (l & 7) ^ lr;      // pre-swizzled source slot
    const ushort* Ab = A  + (size_t)(brow + w * RA + lr) * lda + ls * 8;
    const ushort* Bb = BT + (size_t)(bcol + w * RB + lr) * ldb + ls * 8;

    f32x4 acc[FM][FN];
#pragma unroll
    for (int i = 0; i < FM; ++i)
#pragma unroll
        for (int j = 0; j < FN; ++j) acc[i][j] = (f32x4)0.f;

    for (int k0 = 0; k0 < K; k0 += 64) {
#pragma unroll
        for (int i = 0; i < IA; ++i)
            __builtin_amdgcn_global_load_lds(
                (const __attribute__((address_space(1))) void*)(Ab + (size_t)(i * 8) * lda + k0),
                (__attribute__((address_space(3))) void*)&As[w * RA + i * 8][0],
                16, 0, 0);
#pragma unroll
        for (int i = 0; i < IB; ++i)
            __builtin_amdgcn_global_load_lds(
                (const __attribute__((address_space(1))) void*)(Bb + (size_t)(i * 8) * ldb + k0),
                (__attribute__((address_space(3))) void*)&Bs[w * RB + i * 8][0],
                16, 0, 0);
        __syncthreads();
#pragma unroll
        for (int kh = 0; kh < 2; ++kh) {
            const int slot = (kh * 4 + (l >> 4)) ^ (l & 7);
            bf16x8 af[FM], bfr[FN];
#pragma unroll
            for (int mt = 0; mt < FM; ++mt)
                af[mt] = As[wm * WM + mt * 16 + (l & 15)][slot];
#pragma unroll
            for (int nt = 0; nt < FN; ++nt)
                bfr[nt] = Bs[wn * WN + nt * 16 + (l & 15)][slot];
#pragma unroll
            for (int mt = 0; mt < FM; ++mt)
#pragma unroll
                for (int nt = 0; nt < FN; ++nt)
                    acc[mt][nt] = __builtin_amdgcn_mfma_f32_16x16x32_bf16(
                        af[mt], bfr[nt], acc[mt][nt], 0, 0, 0);
        }
        __syncthreads();
    }

    const int cr = (l >> 4) * 4, cc = l & 15;
#pragma unroll
    for (int mt = 0; mt < FM; ++mt) {
#pragma unroll
        for (int nt = 0; nt < FN; ++nt) {
            const int gc = bcol + wn * WN + nt * 16 + cc;
            const float bv = bias ? bias[gc] : 0.f;
#pragma unroll
            for (int r = 0; r < 4; ++r) {
                const size_t gr = (size_t)brow + wm * WM + mt * 16 + cr + r;
                float v = acc[mt][nt][r] * scale + bv;
                if (GELU) v = 0.5f * v * (1.f + erff(v * 0.70710678118654752f));
                if (res) v += res[gr * ldr + gc];
                if (OUTBF) ((ushort*)Cp)[gr * ldc + gc] = f2bf(v);
                else       ((float*)Cp)[gr * ldc + gc]  = v;
            }
        }
    }
}

// ---------------------------------------------------------------------------
// Layer-0 attend, dots-based: dots[bt][t*128+h*16+m] f32 (scaled+biased),
// v bf16 [bt][m*512+h*64+d]. One block per bt; wave h = head h.
// Lane layout: dg = l&7 (8-d slice), mg = l>>3 (token within group of 8).
// ---------------------------------------------------------------------------
__global__ __launch_bounds__(512) void attend0_k(
    const float* __restrict__ dots, const ushort* __restrict__ vb,
    const int* __restrict__ targets, ushort* __restrict__ o)
{
    const int bt = blockIdx.x;
    const int l  = threadIdx.x & 63;
    const int h  = threadIdx.x >> 6;
    const int dg = l & 7, mg = l >> 3;
    const int t = targets[bt];

    const float* dp = dots + (size_t)bt * NDOT + t * 128 + h * 16;
    float dts[2] = {dp[mg], dp[8 + mg]};

    float mx = fmaxf(dts[0], dts[1]);
#pragma unroll
    for (int off = 8; off < 64; off <<= 1) mx = fmaxf(mx, __shfl_xor(mx, off, 64));
    float e = expf(dts[0] - mx) + expf(dts[1] - mx);
#pragma unroll
    for (int off = 8; off < 64; off <<= 1) e += __shfl_xor(e, off, 64);
    const float lse = mx + logf(e);
    const float a0 = dts[0] - lse, a1 = dts[1] - lse;

    const ushort* base = vb + (size_t)bt * ENW + h * 64 + dg * 8;
    uint4 v0 = *reinterpret_cast<const uint4*>(base + (size_t)mg * EDIM);
    uint4 v1 = *reinterpret_cast<const uint4*>(base + (size_t)(8 + mg) * EDIM);
    const ushort* u0 = reinterpret_cast<const ushort*>(&v0);
    const ushort* u1 = reinterpret_cast<const ushort*>(&v1);
    float acc[8];
#pragma unroll
    for (int j = 0; j < 8; ++j)
        acc[j] = a0 * bf2f(u0[j]) + a1 * bf2f(u1[j]);
#pragma unroll
    for (int off = 8; off < 64; off <<= 1)
#pragma unroll
        for (int j = 0; j < 8; ++j) acc[j] += __shfl_xor(acc[j], off, 64);

    if (mg == 0) {
        uint4 pk;
        pk.x = f2bf(acc[0]) | ((unsigned)f2bf(acc[1]) << 16);
        pk.y = f2bf(acc[2]) | ((unsigned)f2bf(acc[3]) << 16);
        pk.z = f2bf(acc[4]) | ((unsigned)f2bf(acc[5]) << 16);
        pk.w = f2bf(acc[6]) | ((unsigned)f2bf(acc[7]) << 16);
        *reinterpret_cast<uint4*>(o + (size_t)bt * EDIM + h * 64 + dg * 8) = pk;
    }
}

// ---------------------------------------------------------------------------
// Row LayerNorm over E=512: one wave per row; emits f32 AND bf16.
// ---------------------------------------------------------------------------
__global__ __launch_bounds__(256) void ln_k(
    const float* __restrict__ x, const float* __restrict__ g,
    const float* __restrict__ b, float* __restrict__ y,
    ushort* __restrict__ yb)
{
    const int row = blockIdx.x * 4 + (threadIdx.x >> 6);
    const int lane = threadIdx.x & 63;
    const float* xr = x + (size_t)row * EDIM + lane * 8;
    float4 a0 = *reinterpret_cast<const float4*>(xr);
    float4 a1 = *reinterpret_cast<const float4*>(xr + 4);
    float v[8] = {a0.x, a0.y, a0.z, a0.w, a1.x, a1.y, a1.z, a1.w};

    float s = 0.f;
#pragma unroll
    for (int j = 0; j < 8; ++j) s += v[j];
#pragma unroll
    for (int off = 32; off; off >>= 1) s += __shfl_xor(s, off, 64);
    const float m = s * (1.f / 512.f);

    float q = 0.f;
#pragma unroll
    for (int j = 0; j < 8; ++j) { float d = v[j] - m; q = fmaf(d, d, q); }
#pragma unroll
    for (int off = 32; off; off >>= 1) q += __shfl_xor(q, off, 64);
    const float inv = rsqrtf(q * (1.f / 512.f) + 1e-5f);

    const int c = lane * 8;
    float4 g0 = *reinterpret_cast<const float4*>(g + c);
    float4 g1 = *reinterpret_cast<const float4*>(g + c + 4);
    float4 b0 = *reinterpret_cast<const float4*>(b + c);
    float4 b1 = *reinterpret_cast<const float4*>(b + c + 4);
    float gg[8] = {g0.x, g0.y, g0.z, g0.w, g1.x, g1.y, g1.z, g1.w};
    float bb[8] = {b0.x, b0.y, b0.z, b0.w, b1.x, b1.y, b1.z, b1.w};
    float out[8];
#pragma unroll
    for (int j = 0; j < 8; ++j) out[j] = (v[j] - m) * inv * gg[j] + bb[j];
    float* yr = y + (size_t)row * EDIM + c;
    *reinterpret_cast<float4*>(yr) = make_float4(out[0], out[1], out[2], out[3]);
    *reinterpret_cast<float4*>(yr + 4) = make_float4(out[4], out[5], out[6], out[7]);
    uint4 p;
    p.x = f2bf(out[0]) | ((unsigned)f2bf(out[1]) << 16);
    p.y = f2bf(out[2]) | ((unsigned)f2bf(out[3]) << 16);
    p.z = f2bf(out[4]) | ((unsigned)f2bf(out[5]) << 16);
    p.w = f2bf(out[6]) | ((unsigned)f2bf(out[7]) << 16);
    *reinterpret_cast<uint4*>(yb + (size_t)row * EDIM + c) = p;
}

// out[row] = x[row,:] . Wm + bm
__global__ __launch_bounds__(256) void final_k(
    const float* __restrict__ x, const float* __restrict__ Wm,
    const float* __restrict__ bm, float* __restrict__ out)
{
    const int row = blockIdx.x * 4 + (threadIdx.x >> 6);
    const int lane = threadIdx.x & 63;
    const float* xr = x + (size_t)row * EDIM + lane * 8;
    const float* wr = Wm + lane * 8;
    float s = 0.f;
#pragma unroll
    for (int j = 0; j < 8; ++j) s = fmaf(xr[j], wr[j], s);
#pragma unroll
    for (int off = 32; off; off >>= 1) s += __shfl_xor(s, off, 64);
    if (lane == 0) out[row] = s + bm[0];
}

// ---------------------------------------------------------------------------
extern "C" void kernel_launch(void* const* d_in, const int* in_sizes, int n_in,
                              void* d_out, int out_size, void* d_ws, size_t ws_size,
                              hipStream_t stream)
{
    (void)in_sizes; (void)n_in; (void)out_size;
    const float* features = (const float*)d_in[0];
    const int*   targets  = (const int*)d_in[1];
    const float* emb      = (const float*)d_in[2];
    const float* Wf       = (const float*)d_in[3];
    const float* bfv      = (const float*)d_in[4];
    const float* a0Wo     = (const float*)d_in[5];
    const float* a0bo     = (const float*)d_in[6];
    const float* Wm       = (const float*)d_in[7];
    const float* bm       = (const float*)d_in[8];
    const float *ffg[3], *ffb[3], *W1[3], *b1[3], *W2[3], *b2[3];
    for (int i = 0; i < 3; ++i) {
        ffg[i] = (const float*)d_in[9 + 6 * i];
        ffb[i] = (const float*)d_in[10 + 6 * i];
        W1[i]  = (const float*)d_in[11 + 6 * i];
        b1[i]  = (const float*)d_in[12 + 6 * i];
        W2[i]  = (const float*)d_in[13 + 6 * i];
        b2[i]  = (const float*)d_in[14 + 6 * i];
    }
    const float *ag[2], *abp[2], *aWqkv[2], *aWo[2], *abo[2];
    for (int i = 0; i < 2; ++i) {
        ag[i]    = (const float*)d_in[27 + 5 * i];
        abp[i]   = (const float*)d_in[28 + 5 * i];
        aWqkv[i] = (const float*)d_in[29 + 5 * i];
        aWo[i]   = (const float*)d_in[30 + 5 * i];
        abo[i]   = (const float*)d_in[31 + 5 * i];
    }

    // ---- workspace carve-up ----
    char* wsc = (char*)d_ws;
    auto alloc = [&](size_t bytes) { char* p = wsc; wsc += bytes; return p; };
    ushort* WfvT  = (ushort*)alloc((size_t)ENW * INP * 2);       // 25.2 MB (v half)
    ushort* BTg   = (ushort*)alloc((size_t)NDOT * INP * 2);      // 6.3 MB
    float*  C0s   = (float*) alloc((size_t)NDOT * 4);
    float*  dotsb = (float*) alloc((size_t)BTOT * NDOT * 4);     // 33.6 MB
    ushort* a0WoT = (ushort*)alloc((size_t)EDIM * EDIM * 2);
    ushort *W1T[3], *W2T[3], *WoT[2], *Wv_bf[2], *WcombT[2];
    for (int i = 0; i < 3; ++i) {
        W1T[i] = (ushort*)alloc((size_t)FFH * EDIM * 2);
        W2T[i] = (ushort*)alloc((size_t)EDIM * FFH * 2);
    }
    for (int i = 0; i < 2; ++i) {
        WoT[i]    = (ushort*)alloc((size_t)EDIM * EDIM * 2);
        Wv_bf[i]  = (ushort*)alloc((size_t)EDIM * EDIM * 2);
        WcombT[i] = (ushort*)alloc((size_t)EDIM * EDIM * 2);
    }
    ushort* featb = (ushort*)alloc((size_t)BTOT * INP * 2);      // 12.6 MB
    ushort* o_b   = (ushort*)alloc((size_t)BTOT * EDIM * 2);     // 4.2 MB
    float*  x     = (float*) alloc((size_t)BTOT * EDIM * 4);     // 8.4 MB
    float*  xln   = (float*) alloc((size_t)BTOT * EDIM * 4);
    ushort* xlnb  = (ushort*)alloc((size_t)BTOT * EDIM * 2);
    ushort* hb    = (ushort*)alloc((size_t)BTOT * FFH * 2);      // 8.4 MB
    const size_t fixed = (size_t)(wsc - (char*)d_ws);
    int CB = BTOT;
    while (CB > 256 && fixed + (size_t)CB * ENW * 2 > ws_size) CB >>= 1;
    ushort* vb = (ushort*)alloc((size_t)CB * ENW * 2);           // 67 MB @ CB=4096

    const dim3 blk(256, 1, 1);

    // ---- prep: bf16 conversions / weight transposes / G projection ----
    conv_bf16_k<<<(BTOT * INP / 8 + 255) / 256, blk, 0, stream>>>(
        features, featb, BTOT * INP / 8);
    gproj_k<<<128, blk, 0, stream>>>(Wf, bfv, emb, BTg, C0s);
    transpose_bf16_k<<<dim3(ENW / 64, INP / 64), blk, 0, stream>>>(
        Wf, KVW, ENW, INP, WfvT);   // v half of Wf

    TJobs tj;
    tj.j[0] = {a0Wo, a0WoT, EDIM, 0, EDIM, 8, 8};
    for (int i = 0; i < 3; ++i) {
        tj.j[1 + 2 * i] = {W1[i], W1T[i], FFH, 0, EDIM, 16, 8};
        tj.j[2 + 2 * i] = {W2[i], W2T[i], EDIM, 0, FFH, 8, 16};
    }
    tj.j[7] = {aWo[0], WoT[0], EDIM, 0, EDIM, 8, 8};
    tj.j[8] = {aWo[1], WoT[1], EDIM, 0, EDIM, 8, 8};
    transpose_batch_k<<<dim3(16, 16, 9), blk, 0, stream>>>(tj);

    conv_wv_k<<<dim3(128, 2), blk, 0, stream>>>(aWqkv[0], aWqkv[1],
                                                Wv_bf[0], Wv_bf[1]);

    // W_combT = CATT * WoT @ Wv^T  ->  attn layer: x = xln@Wcomb + bo + xln.
    // log_softmax of 16 equal logits = -ln16; o = -16*ln16 * v.
    const float CATT = -44.36141955583650f;
    for (int i = 0; i < 2; ++i)
        gemm_mfma_k<64, 128, 32, 64, 4, false, true>
            <<<dim3(EDIM / 128, EDIM / 64), blk, 0, stream>>>(
            WoT[i], EDIM, Wv_bf[i], EDIM, WcombT[i], EDIM, EDIM,
            nullptr, nullptr, 0, CATT);

    // ---- layer 0 ----
    // dots for ALL 16 targets: dotsb[bt][t*128+hm] = 0.125*(f@G + C0)
    gemm_mfma_k<128, 128, 64, 64, 4, false, false>
        <<<dim3(NDOT / 128, BTOT / 128), blk, 0, stream>>>(
        featb, INP, BTg, INP, dotsb, NDOT, INP, C0s, nullptr, 0, 0.125f);
    // v = f@Wf_v + bf_v (bf16, chunked), then attend from (dots, v)
    for (int c0 = 0; c0 < BTOT; c0 += CB) {
        gemm_mfma_k<128, 128, 64, 64, 4, false, true>
            <<<dim3(ENW / 128, CB / 128), blk, 0, stream>>>(
            featb + (size_t)c0 * INP, INP, WfvT, INP, vb, ENW, INP,
            bfv + ENW, nullptr, 0, 1.f);
        attend0_k<<<CB, 512, 0, stream>>>(dotsb + (size_t)c0 * NDOT, vb,
                                          targets + c0, o_b + (size_t)c0 * EDIM);
    }
    gemm_mfma_k<64, 128, 32, 64, 4, false, false>
        <<<dim3(EDIM / 128, BTOT / 64), blk, 0, stream>>>(
        o_b, EDIM, a0WoT, EDIM, x, EDIM, EDIM, a0bo, nullptr, 0, 1.f);

    auto ln = [&](const float* g, const float* b) {
        ln_k<<<BTOT / 4, blk, 0, stream>>>(x, g, b, xln, xlnb);
    };
    auto ff = [&](int i) {
        ln(ffg[i], ffb[i]);
        gemm_mfma_k<64, 128, 32, 64, 4, true, true>
            <<<dim3(FFH / 128, BTOT / 64), blk, 0, stream>>>(
            xlnb, EDIM, W1T[i], EDIM, hb, FFH, EDIM, b1[i], nullptr, 0, 1.f);
        gemm_mfma_k<64, 128, 32, 64, 4, false, false>
            <<<dim3(EDIM / 128, BTOT / 64), blk, 0, stream>>>(
            hb, FFH, W2T[i], FFH, x, EDIM, FFH, b2[i], xln, EDIM, 1.f);
    };
    auto attn = [&](int i) {
        ln(ag[i], abp[i]);
        gemm_mfma_k<64, 128, 32, 64, 4, false, false>
            <<<dim3(EDIM / 128, BTOT / 64), blk, 0, stream>>>(
            xlnb, EDIM, WcombT[i], EDIM, x, EDIM, EDIM, abo[i], xln, EDIM, 1.f);
    };

    ff(0);
    attn(0);
    ff(1);
    attn(1);
    ff(2);

    final_k<<<BTOT / 4, blk, 0, stream>>>(x, Wm, bm, (float*)d_out);
}

// Round 6
// 493.746 us; speedup vs baseline: 6.0299x; 1.0788x over previous
//
#include <hip/hip_runtime.h>
#include <math.h>

// MixedHead: B=16,T=256 -> BT=4096; INP=1536; E=512; H=8; N=16; D=64.
#define BTOT 4096
#define INP  1536
#define EDIM 512
#define NTOK 16
#define KVW  16384   // 2*E*N
#define ENW  8192    // E*N
#define FFH  1024    // 2*E
#define NDOT 2048    // 16 targets x 128 (h,m)

typedef __attribute__((ext_vector_type(8))) __bf16 bf16x8;
typedef __attribute__((ext_vector_type(4))) float f32x4;

__device__ __forceinline__ ushort f2bf(float f) {
    union { float f; unsigned u; } v; v.f = f;
    unsigned r = v.u + 0x7fffu + ((v.u >> 16) & 1u);
    return (ushort)(r >> 16);
}
__device__ __forceinline__ float bf2f(ushort h) {
    union { unsigned u; float f; } v; v.u = ((unsigned)h) << 16;
    return v.f;
}

// ---------------------------------------------------------------------------
// Transpose f32 [R][ld] (cols c0..) -> bf16 [C][R].  Grid (C/64, R/64).
// ---------------------------------------------------------------------------
__device__ __forceinline__ void transpose_body(
    const float* in, int ld, int c0, int R, ushort* out,
    int bx, int by, int tid)
{
    __shared__ float t[64][65];
    const int bc = bx * 64 + c0;
    const int br = by * 64;
#pragma unroll
    for (int it = 0; it < 16; ++it) {
        int idx = tid + it * 256;
        int r = idx >> 6, c = idx & 63;
        t[r][c] = in[(size_t)(br + r) * ld + bc + c];
    }
    __syncthreads();
    const int C0 = bx * 64;
#pragma unroll
    for (int it = 0; it < 4; ++it) {
        int idx = tid + it * 256;          // 1024 = 64 cols x 16 row-quads
        int cc = idx >> 4, rp = idx & 15;
        uint2 w2;
        w2.x = f2bf(t[4 * rp + 0][cc]) | ((unsigned)f2bf(t[4 * rp + 1][cc]) << 16);
        w2.y = f2bf(t[4 * rp + 2][cc]) | ((unsigned)f2bf(t[4 * rp + 3][cc]) << 16);
        *reinterpret_cast<uint2*>(out + (size_t)(C0 + cc) * R + br + 4 * rp) = w2;
    }
}

__global__ __launch_bounds__(256) void transpose_bf16_k(
    const float* __restrict__ in, int ld, int c0, int R,
    ushort* __restrict__ out)
{
    transpose_body(in, ld, c0, R, out, blockIdx.x, blockIdx.y, threadIdx.x);
}

struct TJob { const float* in; ushort* out; int ld, c0, R, gbx, gby; };
struct TJobs { TJob j[9]; };

__global__ __launch_bounds__(256) void transpose_batch_k(TJobs jobs)
{
    TJob jb = jobs.j[blockIdx.z];
    if ((int)blockIdx.x >= jb.gbx || (int)blockIdx.y >= jb.gby) return;
    transpose_body(jb.in, jb.ld, jb.c0, jb.R, jb.out,
                   blockIdx.x, blockIdx.y, threadIdx.x);
}

// f32 -> bf16 flat convert, 8 elems/thread.
__global__ __launch_bounds__(256) void conv_bf16_k(
    const float* __restrict__ in, ushort* __restrict__ out, int n8)
{
    int i = blockIdx.x * 256 + threadIdx.x;
    if (i >= n8) return;
    const float4* p = reinterpret_cast<const float4*>(in) + 2 * (size_t)i;
    float4 a = p[0], b = p[1];
    uint4 o;
    o.x = f2bf(a.x) | ((unsigned)f2bf(a.y) << 16);
    o.y = f2bf(a.z) | ((unsigned)f2bf(a.w) << 16);
    o.z = f2bf(b.x) | ((unsigned)f2bf(b.y) << 16);
    o.w = f2bf(b.z) | ((unsigned)f2bf(b.w) << 16);
    reinterpret_cast<uint4*>(out)[i] = o;
}

// Strided bf16 convert of the v-slice of Wqkv: out[k][e] = in[k][1024+e].
__global__ __launch_bounds__(256) void conv_wv_k(
    const float* __restrict__ s0, const float* __restrict__ s1,
    ushort* __restrict__ d0, ushort* __restrict__ d1)
{
    const float* src = blockIdx.y ? s1 : s0;
    ushort* dst = blockIdx.y ? d1 : d0;
    int idx = blockIdx.x * 256 + threadIdx.x;   // 32768 total
    int row = idx >> 6, c8 = (idx & 63) * 8;
    const float4* p = reinterpret_cast<const float4*>(
        src + (size_t)row * (3 * EDIM) + 2 * EDIM + c8);
    float4 a = p[0], b = p[1];
    uint4 o;
    o.x = f2bf(a.x) | ((unsigned)f2bf(a.y) << 16);
    o.y = f2bf(a.z) | ((unsigned)f2bf(a.w) << 16);
    o.z = f2bf(b.x) | ((unsigned)f2bf(b.y) << 16);
    o.w = f2bf(b.z) | ((unsigned)f2bf(b.w) << 16);
    *reinterpret_cast<uint4*>(dst + (size_t)row * EDIM + c8) = o;
}

// ---------------------------------------------------------------------------
// G projection: BTg[t*128 + h*16 + m][i] = sum_d Wf[i][m*512+h*64+d]*emb[t][h*64+d]
// (bf16), C0s[n] = 0.125 * sum_d bfv[...]*emb[...] (f32).
// Grid: (128 hm, 8 i-chunks), 256 threads. lane = t(4b) | isub(2b).
// ---------------------------------------------------------------------------
__global__ __launch_bounds__(256) void gproj_k(
    const float* __restrict__ Wf, const float* __restrict__ bfv,
    const float* __restrict__ emb, ushort* __restrict__ BTg,
    float* __restrict__ C0s)
{
    const int hm = blockIdx.x;           // h*16 + m
    const int h = hm >> 4, m = hm & 15;
    const int l = threadIdx.x & 63, w = threadIdx.x >> 6;
    const int t = l & 15, isub = l >> 4;
    const int colb = m * 512 + h * 64;
    const int ibase = blockIdx.y * (INP / 8);

    float4 e[16];
#pragma unroll
    for (int q = 0; q < 16; ++q)
        e[q] = *reinterpret_cast<const float4*>(emb + t * EDIM + h * 64 + q * 4);

    const int n = t * 128 + hm;
    for (int i0 = ibase; i0 < ibase + INP / 8; i0 += 16) {
        const int i = i0 + w * 4 + isub;
        const float* wr = Wf + (size_t)i * KVW + colb;
        float acc = 0.f;
#pragma unroll
        for (int q = 0; q < 16; ++q) {
            float4 v4 = *reinterpret_cast<const float4*>(wr + q * 4);
            acc = fmaf(v4.x, e[q].x, fmaf(v4.y, e[q].y,
                  fmaf(v4.z, e[q].z, fmaf(v4.w, e[q].w, acc))));
        }
        BTg[(size_t)n * INP + i] = f2bf(acc);
    }
    if (blockIdx.y == 0 && w == 0 && isub == 0) {
        const float* br = bfv + colb;
        float acc = 0.f;
#pragma unroll
        for (int q = 0; q < 16; ++q) {
            float4 v4 = *reinterpret_cast<const float4*>(br + q * 4);
            acc = fmaf(v4.x, e[q].x, fmaf(v4.y, e[q].y,
                  fmaf(v4.z, e[q].z, fmaf(v4.w, e[q].w, acc))));
        }
        C0s[n] = 0.125f * acc;
    }
}

// ---------------------------------------------------------------------------
// Counting sort of targets into 16 buckets. Single block, 256 threads.
// perm[pos] = bt grouped by target; boff[17] = bucket offsets (exclusive).
// Slot order within a bucket is non-deterministic but per-row GEMM results
// are tile-position-independent -> final output deterministic.
// ---------------------------------------------------------------------------
__global__ __launch_bounds__(256) void sortperm_k(
    const int* __restrict__ targets, int* __restrict__ perm,
    int* __restrict__ boff)
{
    __shared__ int cnt[NTOK], off[NTOK + 1], cur[NTOK];
    const int tid = threadIdx.x;
    if (tid < NTOK) cnt[tid] = 0;
    __syncthreads();
    for (int i = tid; i < BTOT; i += 256) atomicAdd(&cnt[targets[i]], 1);
    __syncthreads();
    if (tid == 0) {
        int s = 0;
        for (int b = 0; b < NTOK; ++b) { off[b] = s; cur[b] = s; s += cnt[b]; }
        off[NTOK] = s;
        for (int b = 0; b <= NTOK; ++b) boff[b] = off[b];
    }
    __syncthreads();
    for (int i = tid; i < BTOT; i += 256) {
        int t = targets[i];
        int p = atomicAdd(&cur[t], 1);
        perm[p] = i;
    }
}

// ---------------------------------------------------------------------------
// bf16 MFMA GEMM: C[M,N] = epi(scale*A@BT^T + bias [+gelu] [+res])
// A bf16 [M][K] lda=K, BT bf16 [N][K] ldb=K. BMxBN tile, BK=64, NW waves,
// per-wave WMxWN output. LDS [rows][8 x 16B], XOR slot^(row&7); staging via
// global_load_lds with pre-swizzled global source. No XCD swizzle (L3-fit).
// ---------------------------------------------------------------------------
template <int BM, int BN, int WM, int WN, int NW, bool GELU, bool OUTBF>
__global__ __launch_bounds__(NW * 64) void gemm_mfma_k(
    const ushort* __restrict__ A, int lda,
    const ushort* __restrict__ BT, int ldb,
    void* __restrict__ Cp, int ldc, int K,
    const float* __restrict__ bias,
    const float* __restrict__ res, int ldr,
    float scale)
{
    static_assert((BM / WM) * (BN / WN) == NW, "wave grid");
    static_assert(BM % (NW * 8) == 0 && BN % (NW * 8) == 0, "staging");
    constexpr int FM = WM / 16, FN = WN / 16;
    constexpr int IA = BM * 8 / (NW * 64), IB = BN * 8 / (NW * 64);
    constexpr int RA = BM / NW, RB = BN / NW;   // rows staged per wave

    __shared__ bf16x8 As[BM][8];
    __shared__ bf16x8 Bs[BN][8];
    const int tid = threadIdx.x;
    const int l   = tid & 63;
    const int w   = tid >> 6;
    const int wm  = w / (BN / WN), wn = w % (BN / WN);
    const int brow = blockIdx.y * BM, bcol = blockIdx.x * BN;

    const int lr = l >> 3;            // row within 8-row staging segment
    const int ls = (l & 7) ^ lr;      // pre-swizzled source slot
    const ushort* Ab = A  + (size_t)(brow + w * RA + lr) * lda + ls * 8;
    const ushort* Bb = BT + (size_t)(bcol + w * RB + lr) * ldb + ls * 8;

    f32x4 acc[FM][FN];
#pragma unroll
    for (int i = 0; i < FM; ++i)
#pragma unroll
        for (int j = 0; j < FN; ++j) acc[i][j] = (f32x4)0.f;

    for (int k0 = 0; k0 < K; k0 += 64) {
#pragma unroll
        for (int i = 0; i < IA; ++i)
            __builtin_amdgcn_global_load_lds(
                (const __attribute__((address_space(1))) void*)(Ab + (size_t)(i * 8) * lda + k0),
                (__attribute__((address_space(3))) void*)&As[w * RA + i * 8][0],
                16, 0, 0);
#pragma unroll
        for (int i = 0; i < IB; ++i)
            __builtin_amdgcn_global_load_lds(
                (const __attribute__((address_space(1))) void*)(Bb + (size_t)(i * 8) * ldb + k0),
                (__attribute__((address_space(3))) void*)&Bs[w * RB + i * 8][0],
                16, 0, 0);
        __syncthreads();
#pragma unroll
        for (int kh = 0; kh < 2; ++kh) {
            const int slot = (kh * 4 + (l >> 4)) ^ (l & 7);
            bf16x8 af[FM], bfr[FN];
#pragma unroll
            for (int mt = 0; mt < FM; ++mt)
                af[mt] = As[wm * WM + mt * 16 + (l & 15)][slot];
#pragma unroll
            for (int nt = 0; nt < FN; ++nt)
                bfr[nt] = Bs[wn * WN + nt * 16 + (l & 15)][slot];
#pragma unroll
            for (int mt = 0; mt < FM; ++mt)
#pragma unroll
                for (int nt = 0; nt < FN; ++nt)
                    acc[mt][nt] = __builtin_amdgcn_mfma_f32_16x16x32_bf16(
                        af[mt], bfr[nt], acc[mt][nt], 0, 0, 0);
        }
        __syncthreads();
    }

    const int cr = (l >> 4) * 4, cc = l & 15;
#pragma unroll
    for (int mt = 0; mt < FM; ++mt) {
#pragma unroll
        for (int nt = 0; nt < FN; ++nt) {
            const int gc = bcol + wn * WN + nt * 16 + cc;
            const float bv = bias ? bias[gc] : 0.f;
#pragma unroll
            for (int r = 0; r < 4; ++r) {
                const size_t gr = (size_t)brow + wm * WM + mt * 16 + cr + r;
                float v = acc[mt][nt][r] * scale + bv;
                if (GELU) v = 0.5f * v * (1.f + erff(v * 0.70710678118654752f));
                if (res) v += res[gr * ldr + gc];
                if (OUTBF) ((ushort*)Cp)[gr * ldc + gc] = f2bf(v);
                else       ((float*)Cp)[gr * ldc + gc]  = v;
            }
        }
    }
}

// ---------------------------------------------------------------------------
// Bucketed dots GEMM: for rows of bucket b (target t=b), compute
// dots_sel[bt][gc] = 0.125*(f[bt] . BTg[b*128+gc]) + C0s[b*128+gc].
// 128x128 tile, BK=64, 4 waves; A rows indirected through perm.
// Grid (32 tiles, 16 buckets), early-exit on empty tiles; filler lanes
// duplicate the bucket's first row (bit-identical double write, benign).
// ---------------------------------------------------------------------------
__global__ __launch_bounds__(256) void gemm_dots_k(
    const ushort* __restrict__ A,        // featb [BTOT][INP]
    const ushort* __restrict__ BT,       // BTg [NDOT][INP]
    const int* __restrict__ perm, const int* __restrict__ boff,
    const float* __restrict__ C0s, float* __restrict__ Csel)
{
    const int bucket = blockIdx.y;
    const int off = boff[bucket], end = boff[bucket + 1];
    const int tile = blockIdx.x;
    if (tile * 128 >= end - off) return;

    __shared__ bf16x8 As[128][8];
    __shared__ bf16x8 Bs[128][8];
    const int tid = threadIdx.x;
    const int l = tid & 63, w = tid >> 6;
    const int wm = w >> 1, wn = w & 1;
    const int lr = l >> 3;
    const int ls = (l & 7) ^ lr;

    int rowidx[4];
#pragma unroll
    for (int i = 0; i < 4; ++i) {
        int rg = off + tile * 128 + w * 32 + lr + i * 8;
        rowidx[i] = perm[rg < end ? rg : off];
    }
    const ushort* Bb = BT + (size_t)(bucket * 128 + w * 32 + lr) * INP + ls * 8;

    f32x4 acc[4][4];
#pragma unroll
    for (int i = 0; i < 4; ++i)
#pragma unroll
        for (int j = 0; j < 4; ++j) acc[i][j] = (f32x4)0.f;

    for (int k0 = 0; k0 < INP; k0 += 64) {
#pragma unroll
        for (int i = 0; i < 4; ++i)
            __builtin_amdgcn_global_load_lds(
                (const __attribute__((address_space(1))) void*)(
                    A + (size_t)rowidx[i] * INP + ls * 8 + k0),
                (__attribute__((address_space(3))) void*)&As[w * 32 + i * 8][0],
                16, 0, 0);
#pragma unroll
        for (int i = 0; i < 4; ++i)
            __builtin_amdgcn_global_load_lds(
                (const __attribute__((address_space(1))) void*)(
                    Bb + (size_t)(i * 8) * INP + k0),
                (__attribute__((address_space(3))) void*)&Bs[w * 32 + i * 8][0],
                16, 0, 0);
        __syncthreads();
#pragma unroll
        for (int kh = 0; kh < 2; ++kh) {
            const int slot = (kh * 4 + (l >> 4)) ^ (l & 7);
            bf16x8 af[4], bfr[4];
#pragma unroll
            for (int mt = 0; mt < 4; ++mt)
                af[mt] = As[wm * 64 + mt * 16 + (l & 15)][slot];
#pragma unroll
            for (int nt = 0; nt < 4; ++nt)
                bfr[nt] = Bs[wn * 64 + nt * 16 + (l & 15)][slot];
#pragma unroll
            for (int mt = 0; mt < 4; ++mt)
#pragma unroll
                for (int nt = 0; nt < 4; ++nt)
                    acc[mt][nt] = __builtin_amdgcn_mfma_f32_16x16x32_bf16(
                        af[mt], bfr[nt], acc[mt][nt], 0, 0, 0);
        }
        __syncthreads();
    }

    const int cr = (l >> 4) * 4, cc = l & 15;
#pragma unroll
    for (int mt = 0; mt < 4; ++mt) {
#pragma unroll
        for (int nt = 0; nt < 4; ++nt) {
            const int gc = wn * 64 + nt * 16 + cc;
            const float bv = C0s[bucket * 128 + gc];
#pragma unroll
            for (int r = 0; r < 4; ++r) {
                int rg = off + tile * 128 + wm * 64 + mt * 16 + cr + r;
                int orow = perm[rg < end ? rg : off];
                Csel[(size_t)orow * 128 + gc] = acc[mt][nt][r] * 0.125f + bv;
            }
        }
    }
}

// ---------------------------------------------------------------------------
// Layer-0 attend: dots_sel[bt][h*16+m] f32 (scaled+biased), v bf16.
// One block per bt; wave h = head h. dg = l&7 (8-d slice), mg = l>>3.
// ---------------------------------------------------------------------------
__global__ __launch_bounds__(512) void attend0_k(
    const float* __restrict__ dots, const ushort* __restrict__ vb,
    ushort* __restrict__ o)
{
    const int bt = blockIdx.x;
    const int l  = threadIdx.x & 63;
    const int h  = threadIdx.x >> 6;
    const int dg = l & 7, mg = l >> 3;

    const float* dp = dots + (size_t)bt * 128 + h * 16;
    float dts[2] = {dp[mg], dp[8 + mg]};

    float mx = fmaxf(dts[0], dts[1]);
#pragma unroll
    for (int off = 8; off < 64; off <<= 1) mx = fmaxf(mx, __shfl_xor(mx, off, 64));
    float e = expf(dts[0] - mx) + expf(dts[1] - mx);
#pragma unroll
    for (int off = 8; off < 64; off <<= 1) e += __shfl_xor(e, off, 64);
    const float lse = mx + logf(e);
    const float a0 = dts[0] - lse, a1 = dts[1] - lse;

    const ushort* base = vb + (size_t)bt * ENW + h * 64 + dg * 8;
    uint4 v0 = *reinterpret_cast<const uint4*>(base + (size_t)mg * EDIM);
    uint4 v1 = *reinterpret_cast<const uint4*>(base + (size_t)(8 + mg) * EDIM);
    const ushort* u0 = reinterpret_cast<const ushort*>(&v0);
    const ushort* u1 = reinterpret_cast<const ushort*>(&v1);
    float acc[8];
#pragma unroll
    for (int j = 0; j < 8; ++j)
        acc[j] = a0 * bf2f(u0[j]) + a1 * bf2f(u1[j]);
#pragma unroll
    for (int off = 8; off < 64; off <<= 1)
#pragma unroll
        for (int j = 0; j < 8; ++j) acc[j] += __shfl_xor(acc[j], off, 64);

    if (mg == 0) {
        uint4 pk;
        pk.x = f2bf(acc[0]) | ((unsigned)f2bf(acc[1]) << 16);
        pk.y = f2bf(acc[2]) | ((unsigned)f2bf(acc[3]) << 16);
        pk.z = f2bf(acc[4]) | ((unsigned)f2bf(acc[5]) << 16);
        pk.w = f2bf(acc[6]) | ((unsigned)f2bf(acc[7]) << 16);
        *reinterpret_cast<uint4*>(o + (size_t)bt * EDIM + h * 64 + dg * 8) = pk;
    }
}

// ---------------------------------------------------------------------------
// Row LayerNorm over E=512: one wave per row; emits f32 AND bf16.
// ---------------------------------------------------------------------------
__global__ __launch_bounds__(256) void ln_k(
    const float* __restrict__ x, const float* __restrict__ g,
    const float* __restrict__ b, float* __restrict__ y,
    ushort* __restrict__ yb)
{
    const int row = blockIdx.x * 4 + (threadIdx.x >> 6);
    const int lane = threadIdx.x & 63;
    const float* xr = x + (size_t)row * EDIM + lane * 8;
    float4 a0 = *reinterpret_cast<const float4*>(xr);
    float4 a1 = *reinterpret_cast<const float4*>(xr + 4);
    float v[8] = {a0.x, a0.y, a0.z, a0.w, a1.x, a1.y, a1.z, a1.w};

    float s = 0.f;
#pragma unroll
    for (int j = 0; j < 8; ++j) s += v[j];
#pragma unroll
    for (int off = 32; off; off >>= 1) s += __shfl_xor(s, off, 64);
    const float m = s * (1.f / 512.f);

    float q = 0.f;
#pragma unroll
    for (int j = 0; j < 8; ++j) { float d = v[j] - m; q = fmaf(d, d, q); }
#pragma unroll
    for (int off = 32; off; off >>= 1) q += __shfl_xor(q, off, 64);
    const float inv = rsqrtf(q * (1.f / 512.f) + 1e-5f);

    const int c = lane * 8;
    float4 g0 = *reinterpret_cast<const float4*>(g + c);
    float4 g1 = *reinterpret_cast<const float4*>(g + c + 4);
    float4 b0 = *reinterpret_cast<const float4*>(b + c);
    float4 b1 = *reinterpret_cast<const float4*>(b + c + 4);
    float gg[8] = {g0.x, g0.y, g0.z, g0.w, g1.x, g1.y, g1.z, g1.w};
    float bb[8] = {b0.x, b0.y, b0.z, b0.w, b1.x, b1.y, b1.z, b1.w};
    float out[8];
#pragma unroll
    for (int j = 0; j < 8; ++j) out[j] = (v[j] - m) * inv * gg[j] + bb[j];
    float* yr = y + (size_t)row * EDIM + c;
    *reinterpret_cast<float4*>(yr) = make_float4(out[0], out[1], out[2], out[3]);
    *reinterpret_cast<float4*>(yr + 4) = make_float4(out[4], out[5], out[6], out[7]);
    uint4 p;
    p.x = f2bf(out[0]) | ((unsigned)f2bf(out[1]) << 16);
    p.y = f2bf(out[2]) | ((unsigned)f2bf(out[3]) << 16);
    p.z = f2bf(out[4]) | ((unsigned)f2bf(out[5]) << 16);
    p.w = f2bf(out[6]) | ((unsigned)f2bf(out[7]) << 16);
    *reinterpret_cast<uint4*>(yb + (size_t)row * EDIM + c) = p;
}

// out[row] = x[row,:] . Wm + bm
__global__ __launch_bounds__(256) void final_k(
    const float* __restrict__ x, const float* __restrict__ Wm,
    const float* __restrict__ bm, float* __restrict__ out)
{
    const int row = blockIdx.x * 4 + (threadIdx.x >> 6);
    const int lane = threadIdx.x & 63;
    const float* xr = x + (size_t)row * EDIM + lane * 8;
    const float* wr = Wm + lane * 8;
    float s = 0.f;
#pragma unroll
    for (int j = 0; j < 8; ++j) s = fmaf(xr[j], wr[j], s);
#pragma unroll
    for (int off = 32; off; off >>= 1) s += __shfl_xor(s, off, 64);
    if (lane == 0) out[row] = s + bm[0];
}

// ---------------------------------------------------------------------------
extern "C" void kernel_launch(void* const* d_in, const int* in_sizes, int n_in,
                              void* d_out, int out_size, void* d_ws, size_t ws_size,
                              hipStream_t stream)
{
    (void)in_sizes; (void)n_in; (void)out_size;
    const float* features = (const float*)d_in[0];
    const int*   targets  = (const int*)d_in[1];
    const float* emb      = (const float*)d_in[2];
    const float* Wf       = (const float*)d_in[3];
    const float* bfv      = (const float*)d_in[4];
    const float* a0Wo     = (const float*)d_in[5];
    const float* a0bo     = (const float*)d_in[6];
    const float* Wm       = (const float*)d_in[7];
    const float* bm       = (const float*)d_in[8];
    const float *ffg[3], *ffb[3], *W1[3], *b1[3], *W2[3], *b2[3];
    for (int i = 0; i < 3; ++i) {
        ffg[i] = (const float*)d_in[9 + 6 * i];
        ffb[i] = (const float*)d_in[10 + 6 * i];
        W1[i]  = (const float*)d_in[11 + 6 * i];
        b1[i]  = (const float*)d_in[12 + 6 * i];
        W2[i]  = (const float*)d_in[13 + 6 * i];
        b2[i]  = (const float*)d_in[14 + 6 * i];
    }
    const float *ag[2], *abp[2], *aWqkv[2], *aWo[2], *abo[2];
    for (int i = 0; i < 2; ++i) {
        ag[i]    = (const float*)d_in[27 + 5 * i];
        abp[i]   = (const float*)d_in[28 + 5 * i];
        aWqkv[i] = (const float*)d_in[29 + 5 * i];
        aWo[i]   = (const float*)d_in[30 + 5 * i];
        abo[i]   = (const float*)d_in[31 + 5 * i];
    }

    // ---- workspace carve-up ----
    char* wsc = (char*)d_ws;
    auto alloc = [&](size_t bytes) { char* p = wsc; wsc += bytes; return p; };
    ushort* WfvT  = (ushort*)alloc((size_t)ENW * INP * 2);       // 25.2 MB (v half)
    ushort* BTg   = (ushort*)alloc((size_t)NDOT * INP * 2);      // 6.3 MB
    float*  C0s   = (float*) alloc((size_t)NDOT * 4);
    float*  dsel  = (float*) alloc((size_t)BTOT * 128 * 4);      // 2.1 MB
    int*    perm  = (int*)   alloc((size_t)BTOT * 4);
    int*    boff  = (int*)   alloc(32 * 4);
    ushort* a0WoT = (ushort*)alloc((size_t)EDIM * EDIM * 2);
    ushort *W1T[3], *W2T[3], *WoT[2], *Wv_bf[2], *WcombT[2];
    for (int i = 0; i < 3; ++i) {
        W1T[i] = (ushort*)alloc((size_t)FFH * EDIM * 2);
        W2T[i] = (ushort*)alloc((size_t)EDIM * FFH * 2);
    }
    for (int i = 0; i < 2; ++i) {
        WoT[i]    = (ushort*)alloc((size_t)EDIM * EDIM * 2);
        Wv_bf[i]  = (ushort*)alloc((size_t)EDIM * EDIM * 2);
        WcombT[i] = (ushort*)alloc((size_t)EDIM * EDIM * 2);
    }
    ushort* featb = (ushort*)alloc((size_t)BTOT * INP * 2);      // 12.6 MB
    ushort* o_b   = (ushort*)alloc((size_t)BTOT * EDIM * 2);     // 4.2 MB
    float*  x     = (float*) alloc((size_t)BTOT * EDIM * 4);     // 8.4 MB
    float*  xln   = (float*) alloc((size_t)BTOT * EDIM * 4);
    ushort* xlnb  = (ushort*)alloc((size_t)BTOT * EDIM * 2);
    ushort* hb    = (ushort*)alloc((size_t)BTOT * FFH * 2);      // 8.4 MB
    const size_t fixed = (size_t)(wsc - (char*)d_ws);
    int CB = BTOT;
    while (CB > 256 && fixed + (size_t)CB * ENW * 2 > ws_size) CB >>= 1;
    ushort* vb = (ushort*)alloc((size_t)CB * ENW * 2);           // 67 MB @ CB=4096

    const dim3 blk(256, 1, 1);

    // ---- prep: bf16 conversions / weight transposes / G projection ----
    conv_bf16_k<<<(BTOT * INP / 8 + 255) / 256, blk, 0, stream>>>(
        features, featb, BTOT * INP / 8);
    gproj_k<<<dim3(128, 8), blk, 0, stream>>>(Wf, bfv, emb, BTg, C0s);
    sortperm_k<<<1, blk, 0, stream>>>(targets, perm, boff);
    transpose_bf16_k<<<dim3(ENW / 64, INP / 64), blk, 0, stream>>>(
        Wf, KVW, ENW, INP, WfvT);   // v half of Wf

    TJobs tj;
    tj.j[0] = {a0Wo, a0WoT, EDIM, 0, EDIM, 8, 8};
    for (int i = 0; i < 3; ++i) {
        tj.j[1 + 2 * i] = {W1[i], W1T[i], FFH, 0, EDIM, 16, 8};
        tj.j[2 + 2 * i] = {W2[i], W2T[i], EDIM, 0, FFH, 8, 16};
    }
    tj.j[7] = {aWo[0], WoT[0], EDIM, 0, EDIM, 8, 8};
    tj.j[8] = {aWo[1], WoT[1], EDIM, 0, EDIM, 8, 8};
    transpose_batch_k<<<dim3(16, 16, 9), blk, 0, stream>>>(tj);

    conv_wv_k<<<dim3(128, 2), blk, 0, stream>>>(aWqkv[0], aWqkv[1],
                                                Wv_bf[0], Wv_bf[1]);

    // W_combT = CATT * WoT @ Wv^T  ->  attn layer: x = xln@Wcomb + bo + xln.
    // log_softmax of 16 equal logits = -ln16; o = -16*ln16 * v.
    const float CATT = -44.36141955583650f;
    for (int i = 0; i < 2; ++i)
        gemm_mfma_k<64, 128, 32, 64, 4, false, true>
            <<<dim3(EDIM / 128, EDIM / 64), blk, 0, stream>>>(
            WoT[i], EDIM, Wv_bf[i], EDIM, WcombT[i], EDIM, EDIM,
            nullptr, nullptr, 0, CATT);

    // ---- layer 0 ----
    // bucketed dots: dsel[bt][hm] = 0.125*(f.G[t[bt]]) + C0s[t[bt]*128+hm]
    gemm_dots_k<<<dim3(32, 16), blk, 0, stream>>>(featb, BTg, perm, boff,
                                                  C0s, dsel);
    // v = f@Wf_v + bf_v (bf16, chunked), then attend from (dsel, v)
    for (int c0 = 0; c0 < BTOT; c0 += CB) {
        gemm_mfma_k<128, 128, 64, 64, 4, false, true>
            <<<dim3(ENW / 128, CB / 128), blk, 0, stream>>>(
            featb + (size_t)c0 * INP, INP, WfvT, INP, vb, ENW, INP,
            bfv + ENW, nullptr, 0, 1.f);
        attend0_k<<<CB, 512, 0, stream>>>(dsel + (size_t)c0 * 128, vb,
                                          o_b + (size_t)c0 * EDIM);
    }
    gemm_mfma_k<64, 128, 32, 64, 4, false, false>
        <<<dim3(EDIM / 128, BTOT / 64), blk, 0, stream>>>(
        o_b, EDIM, a0WoT, EDIM, x, EDIM, EDIM, a0bo, nullptr, 0, 1.f);

    auto ln = [&](const float* g, const float* b) {
        ln_k<<<BTOT / 4, blk, 0, stream>>>(x, g, b, xln, xlnb);
    };
    auto ff = [&](int i) {
        ln(ffg[i], ffb[i]);
        gemm_mfma_k<64, 128, 32, 64, 4, true, true>
            <<<dim3(FFH / 128, BTOT / 64), blk, 0, stream>>>(
            xlnb, EDIM, W1T[i], EDIM, hb, FFH, EDIM, b1[i], nullptr, 0, 1.f);
        gemm_mfma_k<64, 128, 32, 64, 4, false, false>
            <<<dim3(EDIM / 128, BTOT / 64), blk, 0, stream>>>(
            hb, FFH, W2T[i], FFH, x, EDIM, FFH, b2[i], xln, EDIM, 1.f);
    };
    auto attn = [&](int i) {
        ln(ag[i], abp[i]);
        gemm_mfma_k<64, 128, 32, 64, 4, false, false>
            <<<dim3(EDIM / 128, BTOT / 64), blk, 0, stream>>>(
            xlnb, EDIM, WcombT[i], EDIM, x, EDIM, EDIM, abo[i], xln, EDIM, 1.f);
    };

    ff(0);
    attn(0);
    ff(1);
    attn(1);
    ff(2);

    final_k<<<BTOT / 4, blk, 0, stream>>>(x, Wm, bm, (float*)d_out);
}